// Round 4
// baseline (808.968 us; speedup 1.0000x reference)
//
#include <hip/hip_runtime.h>

// ---------------------------------------------------------------------------
// GAT_4733053960619: SAGEConv(mean) -> ELU -> GAT(2 heads,64) -> ELU -> GAT(1,47)
// N=50000, E=800000, IN_FEATS=256. All fp32.
//
// R3: GEMM occupancy fix. R2's 8x8 tile was correct on paper but VGPR=188
// capped occupancy at 9% (latency-bound at 30% VALU). __launch_bounds__(256,4)
// forces VGPR<=128 (4 waves/SIMD, 16 waves/CU). 128-row tile for all GEMMs.
// ---------------------------------------------------------------------------

__device__ __forceinline__ float wave_sum(float v) {
#pragma unroll
  for (int o = 32; o > 0; o >>= 1) v += __shfl_xor(v, o, 64);
  return v;
}

__device__ __forceinline__ float elu_f(float v) {
  return v > 0.f ? v : __expf(v) - 1.0f;
}

// ---------------- CSR build ----------------
__global__ __launch_bounds__(256) void deg_kernel(const int* __restrict__ dst,
                                                  int* __restrict__ deg, int E) {
  int i = blockIdx.x * 256 + threadIdx.x;
  if (i < E) atomicAdd(&deg[dst[i]], 1);
}

// single-block scan, wave-shuffle based
__global__ __launch_bounds__(1024) void scan_kernel(const int* __restrict__ deg,
                                                    int* __restrict__ row_start, int n) {
  __shared__ int wsum[16];
  __shared__ int wpre[16];
  __shared__ int s_carry;
  const int t = threadIdx.x;
  const int lane = t & 63;
  const int w = t >> 6;
  if (t == 0) s_carry = 0;
  __syncthreads();
  for (int base = 0; base < n; base += 1024) {
    int v = (base + t < n) ? deg[base + t] : 0;
    int inc = v;
#pragma unroll
    for (int o = 1; o < 64; o <<= 1) {
      int u = __shfl_up(inc, o, 64);
      if (lane >= o) inc += u;
    }
    if (lane == 63) wsum[w] = inc;
    __syncthreads();
    if (w == 0 && lane < 16) {
      int s = wsum[lane];
      int p = s;
#pragma unroll
      for (int o = 1; o < 16; o <<= 1) {
        int u = __shfl_up(p, o, 64);
        if (lane >= o) p += u;
      }
      wpre[lane] = p - s;
    }
    __syncthreads();
    int carry = s_carry;
    if (base + t < n) row_start[base + t] = carry + wpre[w] + inc - v;
    __syncthreads();
    if (t == 1023) s_carry = carry + wpre[15] + inc;
    __syncthreads();
  }
  if (t == 0) row_start[n] = s_carry;
}

__global__ __launch_bounds__(256) void scatter_kernel(const int* __restrict__ src,
                                                      const int* __restrict__ dst,
                                                      const int* __restrict__ row_start,
                                                      int* __restrict__ cursor,
                                                      int* __restrict__ csr_src, int E) {
  int i = blockIdx.x * 256 + threadIdx.x;
  if (i < E) {
    int d = dst[i];
    int p = atomicAdd(&cursor[d], 1);
    csr_src[row_start[d] + p] = src[i];
  }
}

// ---------------- fp32 register-tiled GEMM, 128-row tile, 8x8 / 8x4 --------
// C = A @ W. blockIdx.y picks {W0,C0,ilv0} or {W1,C1,ilv1}.
// ilv: logical col gc stored at (gc&63)*2+(gc>>6)  (requires N==128, TN==8).
// Fragment split: cols tc*4 and BN/2+tc*4; rows tr*4 and BM/2+tr*4.
// __launch_bounds__(256,4): cap VGPR at 128 -> 4 waves/SIMD.
template <int BM, int BN, int BK, int TM, int TN>
__global__ __launch_bounds__(256, 4) void gemm_f32(
    const float* __restrict__ A, int lda,
    const float* __restrict__ W0, const float* __restrict__ W1, int ldw,
    float* __restrict__ C0, float* __restrict__ C1, int ldc,
    int M, int N, int K, int ilv0, int ilv1) {
  constexpr int THREADS = (BM / TM) * (BN / TN);
  constexpr int TCN = BN / TN;
  constexpr int A4 = BM * BK / 4 / THREADS;
  constexpr int W4 = BK * BN / 4 / THREADS;
  static_assert(THREADS == 256, "expect 256 threads");
  static_assert(TM == 8 && (TN == 8 || TN == 4), "layout");
  __shared__ float As[BK][BM + 4];
  __shared__ float Ws[BK][BN + 4];

  const float* W = blockIdx.y ? W1 : W0;
  float* C = blockIdx.y ? C1 : C0;
  const int ilv = blockIdx.y ? ilv1 : ilv0;

  const int tid = threadIdx.x;
  const int tc = tid % TCN;
  const int tr = tid / TCN;
  const int row0 = blockIdx.x * BM;

  float4 pa[A4], pw[W4];

  auto loadA = [&](int k0) {
#pragma unroll
    for (int q = 0; q < A4; ++q) {
      int j = tid + q * THREADS;
      int r = j >> 2, kq = j & 3;  // BK==16: 4 float4 per row
      int gr = row0 + r;
      if (gr < M)
        pa[q] = *(const float4*)&A[(size_t)gr * lda + k0 + kq * 4];
      else
        pa[q] = make_float4(0.f, 0.f, 0.f, 0.f);
    }
  };
  auto storeA = [&]() {
#pragma unroll
    for (int q = 0; q < A4; ++q) {
      int j = tid + q * THREADS;
      int r = j >> 2, kq = j & 3;
      As[kq * 4 + 0][r] = pa[q].x;
      As[kq * 4 + 1][r] = pa[q].y;
      As[kq * 4 + 2][r] = pa[q].z;
      As[kq * 4 + 3][r] = pa[q].w;
    }
  };
  auto loadW = [&](int k0) {
#pragma unroll
    for (int q = 0; q < W4; ++q) {
      int j = tid + q * THREADS;
      int r = j / (BN / 4), c4 = j % (BN / 4);
      int gc = c4 * 4;
      const float* wr = W + (size_t)(k0 + r) * ldw + gc;
      if (((ldw & 3) == 0) && gc + 3 < N) {
        pw[q] = *(const float4*)wr;
      } else {
        float4 v = make_float4(0.f, 0.f, 0.f, 0.f);
        if (gc < N) v.x = wr[0];
        if (gc + 1 < N) v.y = wr[1];
        if (gc + 2 < N) v.z = wr[2];
        if (gc + 3 < N) v.w = wr[3];
        pw[q] = v;
      }
    }
  };
  auto storeW = [&]() {
#pragma unroll
    for (int q = 0; q < W4; ++q) {
      int j = tid + q * THREADS;
      int r = j / (BN / 4), c4 = j % (BN / 4);
      *(float4*)&Ws[r][c4 * 4] = pw[q];
    }
  };

  float acc[TM][TN] = {};
  const int nt = K / BK;

  loadA(0);
  loadW(0);

  for (int t = 0; t < nt; ++t) {
    storeA();
    storeW();
    __syncthreads();
    if (t + 1 < nt) {
      loadA((t + 1) * BK);
      loadW((t + 1) * BK);
    }
#pragma unroll
    for (int kk = 0; kk < BK; ++kk) {
      float4 aL = *(const float4*)&As[kk][tr * 4];
      float4 aH = *(const float4*)&As[kk][BM / 2 + tr * 4];
      float4 bL = *(const float4*)&Ws[kk][tc * 4];
      float a[TM], b[TN];
      a[0] = aL.x; a[1] = aL.y; a[2] = aL.z; a[3] = aL.w;
      a[4] = aH.x; a[5] = aH.y; a[6] = aH.z; a[7] = aH.w;
      b[0] = bL.x; b[1] = bL.y; b[2] = bL.z; b[3] = bL.w;
      if constexpr (TN == 8) {
        float4 bH = *(const float4*)&Ws[kk][BN / 2 + tc * 4];
        b[4] = bH.x; b[5] = bH.y; b[6] = bH.z; b[7] = bH.w;
      }
#pragma unroll
      for (int i = 0; i < TM; i++)
#pragma unroll
        for (int j = 0; j < TN; j++) acc[i][j] = fmaf(a[i], b[j], acc[i][j]);
    }
    __syncthreads();
  }

#pragma unroll
  for (int i = 0; i < TM; ++i) {
    int gr = row0 + (i < 4 ? tr * 4 + i : BM / 2 + tr * 4 + (i - 4));
    if (gr >= M) continue;
    float* crow = C + (size_t)gr * ldc;
    if (TN == 8 && ilv) {
#pragma unroll
      for (int j = 0; j < 4; ++j) {
        int gcl = tc * 4 + j;
        *(float2*)&crow[gcl * 2] = make_float2(acc[i][j], acc[i][j + 4]);
      }
    } else {
      int gc0 = tc * 4;
      if (gc0 + 3 < N) {
        *(float4*)&crow[gc0] = make_float4(acc[i][0], acc[i][1], acc[i][2], acc[i][3]);
      } else {
#pragma unroll
        for (int j = 0; j < 4; ++j)
          if (gc0 + j < N) crow[gc0 + j] = acc[i][j];
      }
      if constexpr (TN == 8) {
        int gc1 = BN / 2 + tc * 4;
        if (gc1 + 3 < N) {
          *(float4*)&crow[gc1] = make_float4(acc[i][4], acc[i][5], acc[i][6], acc[i][7]);
        } else {
#pragma unroll
          for (int j = 0; j < 4; ++j)
            if (gc1 + j < N) crow[gc1 + j] = acc[i][4 + j];
        }
      }
    }
  }
}

// ---------------- SAGE aggregation (wave per node) ----------------
__global__ __launch_bounds__(256) void sage_agg(const float* __restrict__ z,
                                                const float2* __restrict__ yI,
                                                const int* __restrict__ row_start,
                                                const int* __restrict__ csr_src,
                                                const float* __restrict__ b,
                                                float* __restrict__ h0, int N) {
  int wid = threadIdx.x >> 6;
  int lane = threadIdx.x & 63;
  int n = blockIdx.x * 4 + wid;
  if (n >= N) return;
  int s = row_start[n], e = row_start[n + 1];
  float a0 = 0.f, a1 = 0.f;
  int i = s;
  for (; i + 1 < e; i += 2) {
    int u0 = csr_src[i], u1 = csr_src[i + 1];
    float2 f0 = yI[(size_t)u0 * 64 + lane];
    float2 f1 = yI[(size_t)u1 * 64 + lane];
    a0 += f0.x + f1.x;
    a1 += f0.y + f1.y;
  }
  if (i < e) {
    float2 f = yI[(size_t)csr_src[i] * 64 + lane];
    a0 += f.x;
    a1 += f.y;
  }
  float inv = 1.0f / fmaxf((float)(e - s), 1.0f);
  size_t base = (size_t)n * 128;
  float v0 = z[base + lane] + a0 * inv + b[lane];
  float v1 = z[base + 64 + lane] + a1 * inv + b[64 + lane];
  h0[base + lane] = elu_f(v0);
  h0[base + 64 + lane] = elu_f(v1);
}

// ---------------- per-node attention logits (layer 1) ----------------------
__global__ __launch_bounds__(256) void elr1_kernel(const float2* __restrict__ featI,
                                                   const float* __restrict__ al,
                                                   const float* __restrict__ ar,
                                                   float2* __restrict__ el,
                                                   float2* __restrict__ er, int N) {
  int wid = threadIdx.x >> 6;
  int lane = threadIdx.x & 63;
  int n = blockIdx.x * 4 + wid;
  if (n >= N) return;
  float2 f = featI[(size_t)n * 64 + lane];
  float e0 = wave_sum(f.x * al[lane]);
  float e1 = wave_sum(f.y * al[64 + lane]);
  float r0 = wave_sum(f.x * ar[lane]);
  float r1 = wave_sum(f.y * ar[64 + lane]);
  if (lane == 0) {
    el[n] = make_float2(e0, e1);
    er[n] = make_float2(r0, r1);
  }
}

// ---------------- attn1: thread per node, softmax weights ------------------
__global__ __launch_bounds__(256) void attn1_kernel(const float2* __restrict__ el,
                                                    const float2* __restrict__ er,
                                                    const int* __restrict__ row_start,
                                                    const int* __restrict__ csr_src,
                                                    float2* __restrict__ alpha,
                                                    float2* __restrict__ inv_s, int N) {
  int n = blockIdx.x * 256 + threadIdx.x;
  if (n >= N) return;
  int beg = row_start[n], end = row_start[n + 1];
  float2 r = er[n];
  float m0 = -INFINITY, m1 = -INFINITY;
  for (int i = beg; i < end; ++i) {
    float2 l = el[csr_src[i]];
    float e0 = l.x + r.x;
    e0 = e0 > 0.f ? e0 : 0.2f * e0;
    float e1 = l.y + r.y;
    e1 = e1 > 0.f ? e1 : 0.2f * e1;
    alpha[i] = make_float2(e0, e1);  // cache logits (sequential)
    m0 = fmaxf(m0, e0);
    m1 = fmaxf(m1, e1);
  }
  float s0 = 0.f, s1 = 0.f;
  for (int i = beg; i < end; ++i) {
    float2 a = alpha[i];
    float p0 = __expf(a.x - m0);
    float p1 = __expf(a.y - m1);
    s0 += p0;
    s1 += p1;
    alpha[i] = make_float2(p0, p1);
  }
  inv_s[n] = make_float2(1.0f / fmaxf(s0, 1e-9f), 1.0f / fmaxf(s1, 1e-9f));
}

// ---------------- fused GAT layer 1 aggregation (wave per node) ------------
__global__ __launch_bounds__(256) void gat1_agg(const float2* __restrict__ featI,
                                                const float2* __restrict__ alpha,
                                                const float2* __restrict__ inv_s,
                                                const int* __restrict__ row_start,
                                                const int* __restrict__ csr_src,
                                                const float* __restrict__ b,
                                                float* __restrict__ h1, int N) {
  int wid = threadIdx.x >> 6;
  int lane = threadIdx.x & 63;
  int n = blockIdx.x * 4 + wid;
  if (n >= N) return;
  int beg = row_start[n], end = row_start[n + 1];
  float a0 = 0.f, a1 = 0.f;
  int i = beg;
  for (; i + 1 < end; i += 2) {
    int u0 = csr_src[i], u1 = csr_src[i + 1];
    float2 p0 = alpha[i], p1 = alpha[i + 1];
    float2 f0 = featI[(size_t)u0 * 64 + lane];
    float2 f1 = featI[(size_t)u1 * 64 + lane];
    a0 = fmaf(p0.x, f0.x, a0);
    a1 = fmaf(p0.y, f0.y, a1);
    a0 = fmaf(p1.x, f1.x, a0);
    a1 = fmaf(p1.y, f1.y, a1);
  }
  if (i < end) {
    float2 p = alpha[i];
    float2 f = featI[(size_t)csr_src[i] * 64 + lane];
    a0 = fmaf(p.x, f.x, a0);
    a1 = fmaf(p.y, f.y, a1);
  }
  float2 is = inv_s[n];
  float o0 = a0 * is.x + b[lane];
  float o1 = a1 * is.y + b[64 + lane];
  size_t base = (size_t)n * 128;
  h1[base + lane] = elu_f(o0);
  h1[base + 64 + lane] = elu_f(o1);
}

// ---------------- per-node attention logits (layer 2) ----------------------
__global__ __launch_bounds__(256) void elr2_kernel(const float* __restrict__ feat,  // ld 48
                                                   const float* __restrict__ al,
                                                   const float* __restrict__ ar,
                                                   float* __restrict__ el,
                                                   float* __restrict__ er, int N) {
  int wid = threadIdx.x >> 6;
  int lane = threadIdx.x & 63;
  int n = blockIdx.x * 4 + wid;
  if (n >= N) return;
  float f = 0.f, a = 0.f, r = 0.f;
  if (lane < 47) {
    f = feat[(size_t)n * 48 + lane];
    a = al[lane];
    r = ar[lane];
  }
  float e = wave_sum(f * a);
  float rr = wave_sum(f * r);
  if (lane == 0) {
    el[n] = e;
    er[n] = rr;
  }
}

// ---------------- attn2: thread per node ----------------------------------
__global__ __launch_bounds__(256) void attn2_kernel(const float* __restrict__ el,
                                                    const float* __restrict__ er,
                                                    const int* __restrict__ row_start,
                                                    const int* __restrict__ csr_src,
                                                    float* __restrict__ alpha,
                                                    float* __restrict__ inv_s, int N) {
  int n = blockIdx.x * 256 + threadIdx.x;
  if (n >= N) return;
  int beg = row_start[n], end = row_start[n + 1];
  float r = er[n];
  float m = -INFINITY;
  for (int i = beg; i < end; ++i) {
    float e = el[csr_src[i]] + r;
    e = e > 0.f ? e : 0.2f * e;
    alpha[i] = e;
    m = fmaxf(m, e);
  }
  float s = 0.f;
  for (int i = beg; i < end; ++i) {
    float p = __expf(alpha[i] - m);
    s += p;
    alpha[i] = p;
  }
  inv_s[n] = 1.0f / fmaxf(s, 1e-9f);
}

// ---------------- fused GAT layer 2 aggregation -> d_out ------------------
__global__ __launch_bounds__(256) void gat2_agg(const float* __restrict__ feat,  // ld 48
                                                const float* __restrict__ alpha,
                                                const float* __restrict__ inv_s,
                                                const int* __restrict__ row_start,
                                                const int* __restrict__ csr_src,
                                                const float* __restrict__ b,
                                                float* __restrict__ out, int N) {
  int wid = threadIdx.x >> 6;
  int lane = threadIdx.x & 63;
  int n = blockIdx.x * 4 + wid;
  if (n >= N) return;
  int beg = row_start[n], end = row_start[n + 1];
  int lidx = lane < 47 ? lane : 0;
  float acc = 0.f;
  int i = beg;
  for (; i + 1 < end; i += 2) {
    int u0 = csr_src[i], u1 = csr_src[i + 1];
    float p0 = alpha[i], p1 = alpha[i + 1];
    acc = fmaf(p0, feat[(size_t)u0 * 48 + lidx], acc);
    acc = fmaf(p1, feat[(size_t)u1 * 48 + lidx], acc);
  }
  if (i < end) {
    acc = fmaf(alpha[i], feat[(size_t)csr_src[i] * 48 + lidx], acc);
  }
  if (lane < 47) {
    out[(size_t)n * 47 + lane] = acc * inv_s[n] + b[lane];
  }
}

// ---------------------------------------------------------------------------
extern "C" void kernel_launch(void* const* d_in, const int* in_sizes, int n_in,
                              void* d_out, int out_size, void* d_ws, size_t ws_size,
                              hipStream_t stream) {
  const float* x = (const float*)d_in[0];
  const int* src = (const int*)d_in[1];
  const int* dst = (const int*)d_in[2];
  const float* sage_w_self = (const float*)d_in[3];
  const float* sage_w_neigh = (const float*)d_in[4];
  const float* sage_b = (const float*)d_in[5];
  const float* gat1_w = (const float*)d_in[6];
  const float* gat1_al = (const float*)d_in[7];
  const float* gat1_ar = (const float*)d_in[8];
  const float* gat1_b = (const float*)d_in[9];
  const float* gat2_w = (const float*)d_in[10];
  const float* gat2_al = (const float*)d_in[11];
  const float* gat2_ar = (const float*)d_in[12];
  const float* gat2_b = (const float*)d_in[13];
  float* out = (float*)d_out;

  const int N = in_sizes[0] / 256;
  const int E = in_sizes[1];

  char* ws = (char*)d_ws;
  size_t off = 0;
  auto alloc = [&](size_t bytes) {
    size_t o = off;
    off += (bytes + 255) & ~(size_t)255;
    return o;
  };
  int* deg_i = (int*)(ws + alloc((size_t)N * 4));
  int* row_start = (int*)(ws + alloc((size_t)(N + 1) * 4));
  int* cursor = (int*)(ws + alloc((size_t)N * 4));
  int* csr_src = (int*)(ws + alloc((size_t)E * 4));
  float* bufA = (float*)(ws + alloc((size_t)N * 128 * 4));
  float* bufB = (float*)(ws + alloc((size_t)N * 128 * 4));
  float* bufC = (float*)(ws + alloc((size_t)N * 128 * 4));
  float2* el1 = (float2*)(ws + alloc((size_t)N * 8));
  float2* er1 = (float2*)(ws + alloc((size_t)N * 8));
  float* el2 = (float*)(ws + alloc((size_t)N * 4));
  float* er2 = (float*)(ws + alloc((size_t)N * 4));
  float2* inv_s1 = (float2*)(ws + alloc((size_t)N * 8));
  float* inv_s2 = (float*)(ws + alloc((size_t)N * 4));
  (void)ws_size;
  (void)n_in;
  (void)out_size;

  float* z = bufA;                 // dead after sage_agg
  float* y = bufB;                 // interleaved; dead after sage_agg
  float* h0 = bufC;                // dead after feat1 gemm
  float* feat1 = bufA;             // interleaved; dead after gat1_agg
  float2* alpha1 = (float2*)bufB;  // dead after gat1_agg
  float* h1 = bufC;                // dead after feat2 gemm
  float* feat2 = bufA;             // ld 48
  float* alpha2 = bufB;

  hipMemsetAsync(deg_i, 0, (size_t)N * 4, stream);
  hipMemsetAsync(cursor, 0, (size_t)N * 4, stream);

  const int eb = (E + 255) / 256;
  const int nb4 = (N + 3) / 4;
  const int nb256 = (N + 255) / 256;

  deg_kernel<<<eb, 256, 0, stream>>>(dst, deg_i, E);
  scan_kernel<<<1, 1024, 0, stream>>>(deg_i, row_start, N);
  scatter_kernel<<<eb, 256, 0, stream>>>(src, dst, row_start, cursor, csr_src, E);

  // layer 0 fused: blockIdx.y=0 -> z = x@W_self (std), y=1 -> yI = x@W_neigh (ilv)
  {
    dim3 grid((N + 127) / 128, 2);
    gemm_f32<128, 128, 16, 8, 8><<<grid, 256, 0, stream>>>(
        x, 256, sage_w_self, sage_w_neigh, 128, z, y, 128, N, 128, 256, 0, 1);
  }
  sage_agg<<<nb4, 256, 0, stream>>>(z, (const float2*)y, row_start, csr_src, sage_b, h0, N);

  // GAT layer 1: feat1 = h0 @ gat1_w (interleaved)
  {
    dim3 grid((N + 127) / 128, 1);
    gemm_f32<128, 128, 16, 8, 8><<<grid, 256, 0, stream>>>(
        h0, 128, gat1_w, gat1_w, 128, feat1, feat1, 128, N, 128, 128, 1, 1);
  }
  elr1_kernel<<<nb4, 256, 0, stream>>>((const float2*)feat1, gat1_al, gat1_ar, el1, er1, N);
  attn1_kernel<<<nb256, 256, 0, stream>>>(el1, er1, row_start, csr_src, alpha1, inv_s1, N);
  gat1_agg<<<nb4, 256, 0, stream>>>((const float2*)feat1, alpha1, inv_s1, row_start,
                                    csr_src, gat1_b, h1, N);

  // GAT layer 2: feat2 = h1 @ gat2_w (ld 48, N=47)
  {
    dim3 grid((N + 127) / 128, 1);
    gemm_f32<128, 64, 16, 8, 4><<<grid, 256, 0, stream>>>(
        h1, 128, gat2_w, gat2_w, 47, feat2, feat2, 48, N, 47, 128, 0, 0);
  }
  elr2_kernel<<<nb4, 256, 0, stream>>>(feat2, gat2_al, gat2_ar, el2, er2, N);
  attn2_kernel<<<nb256, 256, 0, stream>>>(el2, er2, row_start, csr_src, alpha2, inv_s2, N);
  gat2_agg<<<nb4, 256, 0, stream>>>(feat2, alpha2, inv_s2, row_start, csr_src, gat2_b, out, N);
}

// Round 5
// 579.057 us; speedup vs baseline: 1.3970x; 1.3970x over previous
//
#include <hip/hip_runtime.h>

// ---------------------------------------------------------------------------
// GAT_4733053960619: SAGEConv(mean) -> ELU -> GAT(2 heads,64) -> ELU -> GAT(1,47)
// N=50000, E=800000, IN_FEATS=256. All fp32.
//
// R4: GEMMs moved to MFMA (16x16x32 bf16) with split-bf16 fp32 emulation:
// x = hi + lo (both bf16), A@W ~= AhWh + AhWl + AlWh (drop lo*lo ~ 2^-18).
// Wave-per-16-rows, no LDS, no barriers; B^T hi/lo resident in L1/L2.
// agg kernels emit h0/h1 as bf16 hi/lo pairs directly.
// ---------------------------------------------------------------------------

typedef __attribute__((ext_vector_type(8))) short bf16x8;
typedef __attribute__((ext_vector_type(4))) float f32x4;

__device__ __forceinline__ float wave_sum(float v) {
#pragma unroll
  for (int o = 32; o > 0; o >>= 1) v += __shfl_xor(v, o, 64);
  return v;
}

__device__ __forceinline__ float elu_f(float v) {
  return v > 0.f ? v : __expf(v) - 1.0f;
}

__device__ __forceinline__ unsigned short f2bf(float x) {
  union { float f; unsigned u; } v;
  v.f = x;
  unsigned r = v.u + 0x7FFFu + ((v.u >> 16) & 1u);
  return (unsigned short)(r >> 16);
}

__device__ __forceinline__ float bf2f(unsigned short h) {
  union { unsigned u; float f; } v;
  v.u = ((unsigned)h) << 16;
  return v.f;
}

// ---------------- CSR build ----------------
__global__ __launch_bounds__(256) void deg_kernel(const int* __restrict__ dst,
                                                  int* __restrict__ deg, int E) {
  int i = blockIdx.x * 256 + threadIdx.x;
  if (i < E) atomicAdd(&deg[dst[i]], 1);
}

__global__ __launch_bounds__(1024) void scan_kernel(const int* __restrict__ deg,
                                                    int* __restrict__ row_start, int n) {
  __shared__ int wsum[16];
  __shared__ int wpre[16];
  __shared__ int s_carry;
  const int t = threadIdx.x;
  const int lane = t & 63;
  const int w = t >> 6;
  if (t == 0) s_carry = 0;
  __syncthreads();
  for (int base = 0; base < n; base += 1024) {
    int v = (base + t < n) ? deg[base + t] : 0;
    int inc = v;
#pragma unroll
    for (int o = 1; o < 64; o <<= 1) {
      int u = __shfl_up(inc, o, 64);
      if (lane >= o) inc += u;
    }
    if (lane == 63) wsum[w] = inc;
    __syncthreads();
    if (w == 0 && lane < 16) {
      int s = wsum[lane];
      int p = s;
#pragma unroll
      for (int o = 1; o < 16; o <<= 1) {
        int u = __shfl_up(p, o, 64);
        if (lane >= o) p += u;
      }
      wpre[lane] = p - s;
    }
    __syncthreads();
    int carry = s_carry;
    if (base + t < n) row_start[base + t] = carry + wpre[w] + inc - v;
    __syncthreads();
    if (t == 1023) s_carry = carry + wpre[15] + inc;
    __syncthreads();
  }
  if (t == 0) row_start[n] = s_carry;
}

__global__ __launch_bounds__(256) void scatter_kernel(const int* __restrict__ src,
                                                      const int* __restrict__ dst,
                                                      const int* __restrict__ row_start,
                                                      int* __restrict__ cursor,
                                                      int* __restrict__ csr_src, int E) {
  int i = blockIdx.x * 256 + threadIdx.x;
  if (i < E) {
    int d = dst[i];
    int p = atomicAdd(&cursor[d], 1);
    csr_src[row_start[d] + p] = src[i];
  }
}

// ---------------- fp32 -> bf16 hi/lo split (x input) ----------------
__global__ __launch_bounds__(256) void split_x(const float* __restrict__ x,
                                               unsigned short* __restrict__ xh,
                                               unsigned short* __restrict__ xl, int n4) {
  int i = blockIdx.x * 256 + threadIdx.x;
  int stride = gridDim.x * 256;
  for (; i < n4; i += stride) {
    float4 v = ((const float4*)x)[i];
    ushort4 h, l;
    h.x = f2bf(v.x); l.x = f2bf(v.x - bf2f(h.x));
    h.y = f2bf(v.y); l.y = f2bf(v.y - bf2f(h.y));
    h.z = f2bf(v.z); l.z = f2bf(v.z - bf2f(h.z));
    h.w = f2bf(v.w); l.w = f2bf(v.w - bf2f(h.w));
    ((ushort4*)xh)[i] = h;
    ((ushort4*)xl)[i] = l;
  }
}

// ---------------- weight prep: W[K][N] f32 -> W^T hi/lo [Npad][K] bf16 ------
__global__ __launch_bounds__(256) void prep_w(const float* __restrict__ W, int N, int K,
                                              int Npad, unsigned short* __restrict__ th,
                                              unsigned short* __restrict__ tl) {
  int i = blockIdx.x * 256 + threadIdx.x;
  if (i >= Npad * K) return;
  int n = i / K, k = i - n * K;
  float v = (n < N) ? W[(size_t)k * N + n] : 0.f;
  unsigned short h = f2bf(v);
  th[i] = h;
  tl[i] = f2bf(v - bf2f(h));
}

// ---------------- MFMA GEMM: C[M,Ncols] = A @ B, split-bf16 ----------------
// A as hi/lo bf16 [M][K]; B^T as hi/lo bf16 [Npad][K]. Wave per 16 rows.
// blockIdx.y picks {BT0,C0,ilv0} / {BT1,C1,ilv1}.
// ilv: logical col gc stored at (gc&63)*2+(gc>>6)  (head-interleave, Ncols=128).
template <int K, int NT>
__global__ __launch_bounds__(256) void gemm_mfma(
    const unsigned short* __restrict__ Ah, const unsigned short* __restrict__ Al,
    const unsigned short* __restrict__ BTh0, const unsigned short* __restrict__ BTl0,
    const unsigned short* __restrict__ BTh1, const unsigned short* __restrict__ BTl1,
    float* __restrict__ C0, float* __restrict__ C1,
    int ldc, int M, int Ncols, int ilv0, int ilv1) {
  const unsigned short* BTh = blockIdx.y ? BTh1 : BTh0;
  const unsigned short* BTl = blockIdx.y ? BTl1 : BTl0;
  float* C = blockIdx.y ? C1 : C0;
  const int ilv = blockIdx.y ? ilv1 : ilv0;

  const int wid = threadIdx.x >> 6;
  const int lane = threadIdx.x & 63;
  const int lrow = lane & 15;   // A-row / B-col / C-col within tile
  const int kg = lane >> 4;     // k-group (8 elems each)
  const int row0 = blockIdx.x * 64 + wid * 16;
  const int arow = min(row0 + lrow, M - 1);

  f32x4 acc[NT] = {};
  const size_t abase = (size_t)arow * K + kg * 8;
  const size_t bbase = (size_t)lrow * K + kg * 8;

#pragma unroll 1
  for (int kt = 0; kt < K / 32; ++kt) {
    const size_t ka = abase + kt * 32;
    bf16x8 ah = *(const bf16x8*)(Ah + ka);
    bf16x8 al = *(const bf16x8*)(Al + ka);
    const size_t kb = bbase + kt * 32;
#pragma unroll
    for (int nt = 0; nt < NT; ++nt) {
      bf16x8 bh = *(const bf16x8*)(BTh + kb + (size_t)nt * 16 * K);
      bf16x8 bl = *(const bf16x8*)(BTl + kb + (size_t)nt * 16 * K);
      acc[nt] = __builtin_amdgcn_mfma_f32_16x16x32_bf16(ah, bh, acc[nt], 0, 0, 0);
      acc[nt] = __builtin_amdgcn_mfma_f32_16x16x32_bf16(ah, bl, acc[nt], 0, 0, 0);
      acc[nt] = __builtin_amdgcn_mfma_f32_16x16x32_bf16(al, bh, acc[nt], 0, 0, 0);
    }
  }

#pragma unroll
  for (int nt = 0; nt < NT; ++nt) {
    int gc = nt * 16 + lrow;
    if (gc >= Ncols) continue;
    int oc = ilv ? ((gc & 63) * 2 + (gc >> 6)) : gc;
#pragma unroll
    for (int r = 0; r < 4; ++r) {
      int grow = row0 + kg * 4 + r;
      if (grow < M) C[(size_t)grow * ldc + oc] = acc[nt][r];
    }
  }
}

// ---------------- SAGE aggregation (wave per node) -> h0 bf16 hi/lo --------
__global__ __launch_bounds__(256) void sage_agg(const float* __restrict__ z,
                                                const float2* __restrict__ yI,
                                                const int* __restrict__ row_start,
                                                const int* __restrict__ csr_src,
                                                const float* __restrict__ b,
                                                unsigned short* __restrict__ h0h,
                                                unsigned short* __restrict__ h0l, int N) {
  int wid = threadIdx.x >> 6;
  int lane = threadIdx.x & 63;
  int n = blockIdx.x * 4 + wid;
  if (n >= N) return;
  int s = row_start[n], e = row_start[n + 1];
  float a0 = 0.f, a1 = 0.f;
  int i = s;
  for (; i + 1 < e; i += 2) {
    int u0 = csr_src[i], u1 = csr_src[i + 1];
    float2 f0 = yI[(size_t)u0 * 64 + lane];
    float2 f1 = yI[(size_t)u1 * 64 + lane];
    a0 += f0.x + f1.x;
    a1 += f0.y + f1.y;
  }
  if (i < e) {
    float2 f = yI[(size_t)csr_src[i] * 64 + lane];
    a0 += f.x;
    a1 += f.y;
  }
  float inv = 1.0f / fmaxf((float)(e - s), 1.0f);
  size_t base = (size_t)n * 128;
  float v0 = elu_f(z[base + lane] + a0 * inv + b[lane]);
  float v1 = elu_f(z[base + 64 + lane] + a1 * inv + b[64 + lane]);
  unsigned short hh0 = f2bf(v0), hh1 = f2bf(v1);
  h0h[base + lane] = hh0;
  h0l[base + lane] = f2bf(v0 - bf2f(hh0));
  h0h[base + 64 + lane] = hh1;
  h0l[base + 64 + lane] = f2bf(v1 - bf2f(hh1));
}

// ---------------- per-node attention logits (layer 1) ----------------------
__global__ __launch_bounds__(256) void elr1_kernel(const float2* __restrict__ featI,
                                                   const float* __restrict__ al,
                                                   const float* __restrict__ ar,
                                                   float2* __restrict__ el,
                                                   float2* __restrict__ er, int N) {
  int wid = threadIdx.x >> 6;
  int lane = threadIdx.x & 63;
  int n = blockIdx.x * 4 + wid;
  if (n >= N) return;
  float2 f = featI[(size_t)n * 64 + lane];
  float e0 = wave_sum(f.x * al[lane]);
  float e1 = wave_sum(f.y * al[64 + lane]);
  float r0 = wave_sum(f.x * ar[lane]);
  float r1 = wave_sum(f.y * ar[64 + lane]);
  if (lane == 0) {
    el[n] = make_float2(e0, e1);
    er[n] = make_float2(r0, r1);
  }
}

// ---------------- attn1: thread per node, softmax weights ------------------
__global__ __launch_bounds__(256) void attn1_kernel(const float2* __restrict__ el,
                                                    const float2* __restrict__ er,
                                                    const int* __restrict__ row_start,
                                                    const int* __restrict__ csr_src,
                                                    float2* __restrict__ alpha,
                                                    float2* __restrict__ inv_s, int N) {
  int n = blockIdx.x * 256 + threadIdx.x;
  if (n >= N) return;
  int beg = row_start[n], end = row_start[n + 1];
  float2 r = er[n];
  float m0 = -INFINITY, m1 = -INFINITY;
  for (int i = beg; i < end; ++i) {
    float2 l = el[csr_src[i]];
    float e0 = l.x + r.x;
    e0 = e0 > 0.f ? e0 : 0.2f * e0;
    float e1 = l.y + r.y;
    e1 = e1 > 0.f ? e1 : 0.2f * e1;
    alpha[i] = make_float2(e0, e1);
    m0 = fmaxf(m0, e0);
    m1 = fmaxf(m1, e1);
  }
  float s0 = 0.f, s1 = 0.f;
  for (int i = beg; i < end; ++i) {
    float2 a = alpha[i];
    float p0 = __expf(a.x - m0);
    float p1 = __expf(a.y - m1);
    s0 += p0;
    s1 += p1;
    alpha[i] = make_float2(p0, p1);
  }
  inv_s[n] = make_float2(1.0f / fmaxf(s0, 1e-9f), 1.0f / fmaxf(s1, 1e-9f));
}

// ---------------- fused GAT layer 1 aggregation -> h1 bf16 hi/lo -----------
__global__ __launch_bounds__(256) void gat1_agg(const float2* __restrict__ featI,
                                                const float2* __restrict__ alpha,
                                                const float2* __restrict__ inv_s,
                                                const int* __restrict__ row_start,
                                                const int* __restrict__ csr_src,
                                                const float* __restrict__ b,
                                                unsigned short* __restrict__ h1h,
                                                unsigned short* __restrict__ h1l, int N) {
  int wid = threadIdx.x >> 6;
  int lane = threadIdx.x & 63;
  int n = blockIdx.x * 4 + wid;
  if (n >= N) return;
  int beg = row_start[n], end = row_start[n + 1];
  float a0 = 0.f, a1 = 0.f;
  int i = beg;
  for (; i + 1 < end; i += 2) {
    int u0 = csr_src[i], u1 = csr_src[i + 1];
    float2 p0 = alpha[i], p1 = alpha[i + 1];
    float2 f0 = featI[(size_t)u0 * 64 + lane];
    float2 f1 = featI[(size_t)u1 * 64 + lane];
    a0 = fmaf(p0.x, f0.x, a0);
    a1 = fmaf(p0.y, f0.y, a1);
    a0 = fmaf(p1.x, f1.x, a0);
    a1 = fmaf(p1.y, f1.y, a1);
  }
  if (i < end) {
    float2 p = alpha[i];
    float2 f = featI[(size_t)csr_src[i] * 64 + lane];
    a0 = fmaf(p.x, f.x, a0);
    a1 = fmaf(p.y, f.y, a1);
  }
  float2 is = inv_s[n];
  float o0 = elu_f(a0 * is.x + b[lane]);
  float o1 = elu_f(a1 * is.y + b[64 + lane]);
  size_t base = (size_t)n * 128;
  unsigned short hh0 = f2bf(o0), hh1 = f2bf(o1);
  h1h[base + lane] = hh0;
  h1l[base + lane] = f2bf(o0 - bf2f(hh0));
  h1h[base + 64 + lane] = hh1;
  h1l[base + 64 + lane] = f2bf(o1 - bf2f(hh1));
}

// ---------------- per-node attention logits (layer 2) ----------------------
__global__ __launch_bounds__(256) void elr2_kernel(const float* __restrict__ feat,  // ld 48
                                                   const float* __restrict__ al,
                                                   const float* __restrict__ ar,
                                                   float* __restrict__ el,
                                                   float* __restrict__ er, int N) {
  int wid = threadIdx.x >> 6;
  int lane = threadIdx.x & 63;
  int n = blockIdx.x * 4 + wid;
  if (n >= N) return;
  float f = 0.f, a = 0.f, r = 0.f;
  if (lane < 47) {
    f = feat[(size_t)n * 48 + lane];
    a = al[lane];
    r = ar[lane];
  }
  float e = wave_sum(f * a);
  float rr = wave_sum(f * r);
  if (lane == 0) {
    el[n] = e;
    er[n] = rr;
  }
}

// ---------------- attn2: thread per node ----------------------------------
__global__ __launch_bounds__(256) void attn2_kernel(const float* __restrict__ el,
                                                    const float* __restrict__ er,
                                                    const int* __restrict__ row_start,
                                                    const int* __restrict__ csr_src,
                                                    float* __restrict__ alpha,
                                                    float* __restrict__ inv_s, int N) {
  int n = blockIdx.x * 256 + threadIdx.x;
  if (n >= N) return;
  int beg = row_start[n], end = row_start[n + 1];
  float r = er[n];
  float m = -INFINITY;
  for (int i = beg; i < end; ++i) {
    float e = el[csr_src[i]] + r;
    e = e > 0.f ? e : 0.2f * e;
    alpha[i] = e;
    m = fmaxf(m, e);
  }
  float s = 0.f;
  for (int i = beg; i < end; ++i) {
    float p = __expf(alpha[i] - m);
    s += p;
    alpha[i] = p;
  }
  inv_s[n] = 1.0f / fmaxf(s, 1e-9f);
}

// ---------------- fused GAT layer 2 aggregation -> d_out ------------------
__global__ __launch_bounds__(256) void gat2_agg(const float* __restrict__ feat,  // ld 48
                                                const float* __restrict__ alpha,
                                                const float* __restrict__ inv_s,
                                                const int* __restrict__ row_start,
                                                const int* __restrict__ csr_src,
                                                const float* __restrict__ b,
                                                float* __restrict__ out, int N) {
  int wid = threadIdx.x >> 6;
  int lane = threadIdx.x & 63;
  int n = blockIdx.x * 4 + wid;
  if (n >= N) return;
  int beg = row_start[n], end = row_start[n + 1];
  int lidx = lane < 47 ? lane : 0;
  float acc = 0.f;
  int i = beg;
  for (; i + 1 < end; i += 2) {
    int u0 = csr_src[i], u1 = csr_src[i + 1];
    float p0 = alpha[i], p1 = alpha[i + 1];
    acc = fmaf(p0, feat[(size_t)u0 * 48 + lidx], acc);
    acc = fmaf(p1, feat[(size_t)u1 * 48 + lidx], acc);
  }
  if (i < end) {
    acc = fmaf(alpha[i], feat[(size_t)csr_src[i] * 48 + lidx], acc);
  }
  if (lane < 47) {
    out[(size_t)n * 47 + lane] = acc * inv_s[n] + b[lane];
  }
}

// ---------------------------------------------------------------------------
extern "C" void kernel_launch(void* const* d_in, const int* in_sizes, int n_in,
                              void* d_out, int out_size, void* d_ws, size_t ws_size,
                              hipStream_t stream) {
  const float* x = (const float*)d_in[0];
  const int* src = (const int*)d_in[1];
  const int* dst = (const int*)d_in[2];
  const float* sage_w_self = (const float*)d_in[3];
  const float* sage_w_neigh = (const float*)d_in[4];
  const float* sage_b = (const float*)d_in[5];
  const float* gat1_w = (const float*)d_in[6];
  const float* gat1_al = (const float*)d_in[7];
  const float* gat1_ar = (const float*)d_in[8];
  const float* gat1_b = (const float*)d_in[9];
  const float* gat2_w = (const float*)d_in[10];
  const float* gat2_al = (const float*)d_in[11];
  const float* gat2_ar = (const float*)d_in[12];
  const float* gat2_b = (const float*)d_in[13];
  float* out = (float*)d_out;

  const int N = in_sizes[0] / 256;
  const int E = in_sizes[1];

  char* ws = (char*)d_ws;
  size_t off = 0;
  auto alloc = [&](size_t bytes) {
    size_t o = off;
    off += (bytes + 255) & ~(size_t)255;
    return o;
  };
  int* deg_i = (int*)(ws + alloc((size_t)N * 4));
  int* row_start = (int*)(ws + alloc((size_t)(N + 1) * 4));
  int* cursor = (int*)(ws + alloc((size_t)N * 4));
  int* csr_src = (int*)(ws + alloc((size_t)E * 4));
  float* bufA = (float*)(ws + alloc((size_t)N * 128 * 4));   // z -> feat1 -> feat2
  float* bufB = (float*)(ws + alloc((size_t)N * 128 * 4));   // yI -> alpha1 -> alpha2
  unsigned short* bufX = (unsigned short*)(ws + alloc((size_t)N * 256 * 2 * 2));  // xh|xl
  // weight transposes (hi/lo), padded cols
  unsigned short* wt_sh = (unsigned short*)(ws + alloc(128 * 256 * 2));
  unsigned short* wt_sl = (unsigned short*)(ws + alloc(128 * 256 * 2));
  unsigned short* wt_nh = (unsigned short*)(ws + alloc(128 * 256 * 2));
  unsigned short* wt_nl = (unsigned short*)(ws + alloc(128 * 256 * 2));
  unsigned short* wt_1h = (unsigned short*)(ws + alloc(128 * 128 * 2));
  unsigned short* wt_1l = (unsigned short*)(ws + alloc(128 * 128 * 2));
  unsigned short* wt_2h = (unsigned short*)(ws + alloc(48 * 128 * 2));
  unsigned short* wt_2l = (unsigned short*)(ws + alloc(48 * 128 * 2));
  float2* el1 = (float2*)(ws + alloc((size_t)N * 8));
  float2* er1 = (float2*)(ws + alloc((size_t)N * 8));
  float* el2 = (float*)(ws + alloc((size_t)N * 4));
  float* er2 = (float*)(ws + alloc((size_t)N * 4));
  float2* inv_s1 = (float2*)(ws + alloc((size_t)N * 8));
  float* inv_s2 = (float*)(ws + alloc((size_t)N * 4));
  (void)ws_size;
  (void)n_in;
  (void)out_size;

  // lifetimes:
  unsigned short* xh = bufX;                        // dead after L0 gemm
  unsigned short* xl = bufX + (size_t)N * 256;      // dead after L0 gemm
  float* z = bufA;
  float* yI = bufB;
  unsigned short* h0h = bufX;                       // reuse xh region
  unsigned short* h0l = bufX + (size_t)N * 128;
  float* feat1 = bufA;
  float2* alpha1 = (float2*)bufB;
  unsigned short* h1h = bufX + (size_t)N * 256;     // reuse xl region
  unsigned short* h1l = bufX + (size_t)N * 256 + (size_t)N * 128;
  float* feat2 = bufA;  // ld 48
  float* alpha2 = bufB;

  hipMemsetAsync(deg_i, 0, (size_t)N * 4, stream);
  hipMemsetAsync(cursor, 0, (size_t)N * 4, stream);

  const int eb = (E + 255) / 256;
  const int nb4 = (N + 3) / 4;
  const int nb256 = (N + 255) / 256;
  const int gx = (N + 63) / 64;  // M-tiles for gemm_mfma

  // prep: split x, transpose+split weights
  split_x<<<2048, 256, 0, stream>>>(x, xh, xl, N * 64);  // N*256/4 float4s
  prep_w<<<(128 * 256 + 255) / 256, 256, 0, stream>>>(sage_w_self, 128, 256, 128, wt_sh, wt_sl);
  prep_w<<<(128 * 256 + 255) / 256, 256, 0, stream>>>(sage_w_neigh, 128, 256, 128, wt_nh, wt_nl);
  prep_w<<<(128 * 128 + 255) / 256, 256, 0, stream>>>(gat1_w, 128, 128, 128, wt_1h, wt_1l);
  prep_w<<<(48 * 128 + 255) / 256, 256, 0, stream>>>(gat2_w, 47, 128, 48, wt_2h, wt_2l);

  deg_kernel<<<eb, 256, 0, stream>>>(dst, deg_i, E);
  scan_kernel<<<1, 1024, 0, stream>>>(deg_i, row_start, N);
  scatter_kernel<<<eb, 256, 0, stream>>>(src, dst, row_start, cursor, csr_src, E);

  // layer 0: y=0 -> z = x@W_self (std), y=1 -> yI = x@W_neigh (ilv)
  {
    dim3 grid(gx, 2);
    gemm_mfma<256, 8><<<grid, 256, 0, stream>>>(xh, xl, wt_sh, wt_sl, wt_nh, wt_nl,
                                                z, yI, 128, N, 128, 0, 1);
  }
  sage_agg<<<nb4, 256, 0, stream>>>(z, (const float2*)yI, row_start, csr_src, sage_b,
                                    h0h, h0l, N);

  // GAT layer 1: feat1 = h0 @ gat1_w (interleaved)
  {
    dim3 grid(gx, 1);
    gemm_mfma<128, 8><<<grid, 256, 0, stream>>>(h0h, h0l, wt_1h, wt_1l, wt_1h, wt_1l,
                                                feat1, feat1, 128, N, 128, 1, 1);
  }
  elr1_kernel<<<nb4, 256, 0, stream>>>((const float2*)feat1, gat1_al, gat1_ar, el1, er1, N);
  attn1_kernel<<<nb256, 256, 0, stream>>>(el1, er1, row_start, csr_src, alpha1, inv_s1, N);
  gat1_agg<<<nb4, 256, 0, stream>>>((const float2*)feat1, alpha1, inv_s1, row_start,
                                    csr_src, gat1_b, h1h, h1l, N);

  // GAT layer 2: feat2 = h1 @ gat2_w (ld 48, Ncols=47)
  {
    dim3 grid(gx, 1);
    gemm_mfma<128, 3><<<grid, 256, 0, stream>>>(h1h, h1l, wt_2h, wt_2l, wt_2h, wt_2l,
                                                feat2, feat2, 48, N, 47, 0, 0);
  }
  elr2_kernel<<<nb4, 256, 0, stream>>>(feat2, gat2_al, gat2_ar, el2, er2, N);
  attn2_kernel<<<nb256, 256, 0, stream>>>(el2, er2, row_start, csr_src, alpha2, inv_s2, N);
  gat2_agg<<<nb4, 256, 0, stream>>>(feat2, alpha2, inv_s2, row_start, csr_src, gat2_b, out, N);
}

// Round 6
// 526.210 us; speedup vs baseline: 1.5373x; 1.1004x over previous
//
#include <hip/hip_runtime.h>

// ---------------------------------------------------------------------------
// GAT_4733053960619: SAGEConv(mean) -> ELU -> GAT(2 heads,64) -> ELU -> GAT(1,47)
// N=50000, E=800000, IN_FEATS=256. All fp32.
//
// R5: gemm_mfma density fix. R4 was VMEM-latency-bound (MfmaUtil 6%): 3 MFMAs
// per B-load pair, unroll 1 serialized loads/compute. Now: 2 row-fragments per
// wave (32 rows) -> 6 MFMAs per B-load pair + half the B^T re-read traffic;
// unroll 2 gives the scheduler a prefetch window. No forced launch bounds
// (R3 lesson: spills masquerade as occupancy fixes).
// ---------------------------------------------------------------------------

typedef __attribute__((ext_vector_type(8))) short bf16x8;
typedef __attribute__((ext_vector_type(4))) float f32x4;

__device__ __forceinline__ float wave_sum(float v) {
#pragma unroll
  for (int o = 32; o > 0; o >>= 1) v += __shfl_xor(v, o, 64);
  return v;
}

__device__ __forceinline__ float elu_f(float v) {
  return v > 0.f ? v : __expf(v) - 1.0f;
}

__device__ __forceinline__ unsigned short f2bf(float x) {
  union { float f; unsigned u; } v;
  v.f = x;
  unsigned r = v.u + 0x7FFFu + ((v.u >> 16) & 1u);
  return (unsigned short)(r >> 16);
}

__device__ __forceinline__ float bf2f(unsigned short h) {
  union { unsigned u; float f; } v;
  v.u = ((unsigned)h) << 16;
  return v.f;
}

// ---------------- CSR build ----------------
__global__ __launch_bounds__(256) void deg_kernel(const int* __restrict__ dst,
                                                  int* __restrict__ deg, int E) {
  int i = blockIdx.x * 256 + threadIdx.x;
  if (i < E) atomicAdd(&deg[dst[i]], 1);
}

__global__ __launch_bounds__(1024) void scan_kernel(const int* __restrict__ deg,
                                                    int* __restrict__ row_start, int n) {
  __shared__ int wsum[16];
  __shared__ int wpre[16];
  __shared__ int s_carry;
  const int t = threadIdx.x;
  const int lane = t & 63;
  const int w = t >> 6;
  if (t == 0) s_carry = 0;
  __syncthreads();
  for (int base = 0; base < n; base += 1024) {
    int v = (base + t < n) ? deg[base + t] : 0;
    int inc = v;
#pragma unroll
    for (int o = 1; o < 64; o <<= 1) {
      int u = __shfl_up(inc, o, 64);
      if (lane >= o) inc += u;
    }
    if (lane == 63) wsum[w] = inc;
    __syncthreads();
    if (w == 0 && lane < 16) {
      int s = wsum[lane];
      int p = s;
#pragma unroll
      for (int o = 1; o < 16; o <<= 1) {
        int u = __shfl_up(p, o, 64);
        if (lane >= o) p += u;
      }
      wpre[lane] = p - s;
    }
    __syncthreads();
    int carry = s_carry;
    if (base + t < n) row_start[base + t] = carry + wpre[w] + inc - v;
    __syncthreads();
    if (t == 1023) s_carry = carry + wpre[15] + inc;
    __syncthreads();
  }
  if (t == 0) row_start[n] = s_carry;
}

__global__ __launch_bounds__(256) void scatter_kernel(const int* __restrict__ src,
                                                      const int* __restrict__ dst,
                                                      const int* __restrict__ row_start,
                                                      int* __restrict__ cursor,
                                                      int* __restrict__ csr_src, int E) {
  int i = blockIdx.x * 256 + threadIdx.x;
  if (i < E) {
    int d = dst[i];
    int p = atomicAdd(&cursor[d], 1);
    csr_src[row_start[d] + p] = src[i];
  }
}

// ---------------- fp32 -> bf16 hi/lo split (x input) ----------------
__global__ __launch_bounds__(256) void split_x(const float* __restrict__ x,
                                               unsigned short* __restrict__ xh,
                                               unsigned short* __restrict__ xl, int n4) {
  int i = blockIdx.x * 256 + threadIdx.x;
  int stride = gridDim.x * 256;
  for (; i < n4; i += stride) {
    float4 v = ((const float4*)x)[i];
    ushort4 h, l;
    h.x = f2bf(v.x); l.x = f2bf(v.x - bf2f(h.x));
    h.y = f2bf(v.y); l.y = f2bf(v.y - bf2f(h.y));
    h.z = f2bf(v.z); l.z = f2bf(v.z - bf2f(h.z));
    h.w = f2bf(v.w); l.w = f2bf(v.w - bf2f(h.w));
    ((ushort4*)xh)[i] = h;
    ((ushort4*)xl)[i] = l;
  }
}

// ---------------- weight prep: W[K][N] f32 -> W^T hi/lo [Npad][K] bf16 ------
__global__ __launch_bounds__(256) void prep_w(const float* __restrict__ W, int N, int K,
                                              int Npad, unsigned short* __restrict__ th,
                                              unsigned short* __restrict__ tl) {
  int i = blockIdx.x * 256 + threadIdx.x;
  if (i >= Npad * K) return;
  int n = i / K, k = i - n * K;
  float v = (n < N) ? W[(size_t)k * N + n] : 0.f;
  unsigned short h = f2bf(v);
  th[i] = h;
  tl[i] = f2bf(v - bf2f(h));
}

// ---------------- MFMA GEMM: C[M,Ncols] = A @ B, split-bf16 ----------------
// A as hi/lo bf16 [M][K]; B^T as hi/lo bf16 [Npad][K].
// Wave computes 32 rows (2 x 16-row fragments) x NT*16 cols; block = 4 waves
// = 128 rows. Same B fragment feeds 6 MFMAs (2 row-frags x 3 split terms).
// blockIdx.y picks {BT0,C0,ilv0} / {BT1,C1,ilv1}.
// ilv: logical col gc stored at (gc&63)*2+(gc>>6)  (head-interleave, Ncols=128).
template <int K, int NT>
__global__ __launch_bounds__(256) void gemm_mfma(
    const unsigned short* __restrict__ Ah, const unsigned short* __restrict__ Al,
    const unsigned short* __restrict__ BTh0, const unsigned short* __restrict__ BTl0,
    const unsigned short* __restrict__ BTh1, const unsigned short* __restrict__ BTl1,
    float* __restrict__ C0, float* __restrict__ C1,
    int ldc, int M, int Ncols, int ilv0, int ilv1) {
  const unsigned short* BTh = blockIdx.y ? BTh1 : BTh0;
  const unsigned short* BTl = blockIdx.y ? BTl1 : BTl0;
  float* C = blockIdx.y ? C1 : C0;
  const int ilv = blockIdx.y ? ilv1 : ilv0;

  const int wid = threadIdx.x >> 6;
  const int lane = threadIdx.x & 63;
  const int lrow = lane & 15;   // A-row / B-col within 16-tile
  const int kg = lane >> 4;     // k-group (8 elems each)
  const int row0 = blockIdx.x * 128 + wid * 32;
  const int ra = min(row0 + lrow, M - 1);
  const int rb = min(row0 + 16 + lrow, M - 1);

  f32x4 accA[NT] = {};
  f32x4 accB[NT] = {};
  const size_t aoffA = (size_t)ra * K + kg * 8;
  const size_t aoffB = (size_t)rb * K + kg * 8;
  const size_t boff = (size_t)lrow * K + kg * 8;

#pragma unroll 2
  for (int kt = 0; kt < K / 32; ++kt) {
    const int ko = kt * 32;
    bf16x8 ahA = *(const bf16x8*)(Ah + aoffA + ko);
    bf16x8 alA = *(const bf16x8*)(Al + aoffA + ko);
    bf16x8 ahB = *(const bf16x8*)(Ah + aoffB + ko);
    bf16x8 alB = *(const bf16x8*)(Al + aoffB + ko);
#pragma unroll
    for (int nt = 0; nt < NT; ++nt) {
      const size_t kb = boff + ko + (size_t)nt * 16 * K;
      bf16x8 bh = *(const bf16x8*)(BTh + kb);
      bf16x8 bl = *(const bf16x8*)(BTl + kb);
      accA[nt] = __builtin_amdgcn_mfma_f32_16x16x32_bf16(ahA, bh, accA[nt], 0, 0, 0);
      accA[nt] = __builtin_amdgcn_mfma_f32_16x16x32_bf16(ahA, bl, accA[nt], 0, 0, 0);
      accA[nt] = __builtin_amdgcn_mfma_f32_16x16x32_bf16(alA, bh, accA[nt], 0, 0, 0);
      accB[nt] = __builtin_amdgcn_mfma_f32_16x16x32_bf16(ahB, bh, accB[nt], 0, 0, 0);
      accB[nt] = __builtin_amdgcn_mfma_f32_16x16x32_bf16(ahB, bl, accB[nt], 0, 0, 0);
      accB[nt] = __builtin_amdgcn_mfma_f32_16x16x32_bf16(alB, bh, accB[nt], 0, 0, 0);
    }
  }

#pragma unroll
  for (int nt = 0; nt < NT; ++nt) {
    int gc = nt * 16 + lrow;
    if (gc >= Ncols) continue;
    int oc = ilv ? ((gc & 63) * 2 + (gc >> 6)) : gc;
#pragma unroll
    for (int r = 0; r < 4; ++r) {
      int g0 = row0 + kg * 4 + r;
      if (g0 < M) C[(size_t)g0 * ldc + oc] = accA[nt][r];
      int g1 = row0 + 16 + kg * 4 + r;
      if (g1 < M) C[(size_t)g1 * ldc + oc] = accB[nt][r];
    }
  }
}

// ---------------- SAGE aggregation (wave per node) -> h0 bf16 hi/lo --------
__global__ __launch_bounds__(256) void sage_agg(const float* __restrict__ z,
                                                const float2* __restrict__ yI,
                                                const int* __restrict__ row_start,
                                                const int* __restrict__ csr_src,
                                                const float* __restrict__ b,
                                                unsigned short* __restrict__ h0h,
                                                unsigned short* __restrict__ h0l, int N) {
  int wid = threadIdx.x >> 6;
  int lane = threadIdx.x & 63;
  int n = blockIdx.x * 4 + wid;
  if (n >= N) return;
  int s = row_start[n], e = row_start[n + 1];
  float a0 = 0.f, a1 = 0.f;
  int i = s;
  for (; i + 1 < e; i += 2) {
    int u0 = csr_src[i], u1 = csr_src[i + 1];
    float2 f0 = yI[(size_t)u0 * 64 + lane];
    float2 f1 = yI[(size_t)u1 * 64 + lane];
    a0 += f0.x + f1.x;
    a1 += f0.y + f1.y;
  }
  if (i < e) {
    float2 f = yI[(size_t)csr_src[i] * 64 + lane];
    a0 += f.x;
    a1 += f.y;
  }
  float inv = 1.0f / fmaxf((float)(e - s), 1.0f);
  size_t base = (size_t)n * 128;
  float v0 = elu_f(z[base + lane] + a0 * inv + b[lane]);
  float v1 = elu_f(z[base + 64 + lane] + a1 * inv + b[64 + lane]);
  unsigned short hh0 = f2bf(v0), hh1 = f2bf(v1);
  h0h[base + lane] = hh0;
  h0l[base + lane] = f2bf(v0 - bf2f(hh0));
  h0h[base + 64 + lane] = hh1;
  h0l[base + 64 + lane] = f2bf(v1 - bf2f(hh1));
}

// ---------------- per-node attention logits (layer 1) ----------------------
__global__ __launch_bounds__(256) void elr1_kernel(const float2* __restrict__ featI,
                                                   const float* __restrict__ al,
                                                   const float* __restrict__ ar,
                                                   float2* __restrict__ el,
                                                   float2* __restrict__ er, int N) {
  int wid = threadIdx.x >> 6;
  int lane = threadIdx.x & 63;
  int n = blockIdx.x * 4 + wid;
  if (n >= N) return;
  float2 f = featI[(size_t)n * 64 + lane];
  float e0 = wave_sum(f.x * al[lane]);
  float e1 = wave_sum(f.y * al[64 + lane]);
  float r0 = wave_sum(f.x * ar[lane]);
  float r1 = wave_sum(f.y * ar[64 + lane]);
  if (lane == 0) {
    el[n] = make_float2(e0, e1);
    er[n] = make_float2(r0, r1);
  }
}

// ---------------- attn1: thread per node, softmax weights ------------------
__global__ __launch_bounds__(256) void attn1_kernel(const float2* __restrict__ el,
                                                    const float2* __restrict__ er,
                                                    const int* __restrict__ row_start,
                                                    const int* __restrict__ csr_src,
                                                    float2* __restrict__ alpha,
                                                    float2* __restrict__ inv_s, int N) {
  int n = blockIdx.x * 256 + threadIdx.x;
  if (n >= N) return;
  int beg = row_start[n], end = row_start[n + 1];
  float2 r = er[n];
  float m0 = -INFINITY, m1 = -INFINITY;
  for (int i = beg; i < end; ++i) {
    float2 l = el[csr_src[i]];
    float e0 = l.x + r.x;
    e0 = e0 > 0.f ? e0 : 0.2f * e0;
    float e1 = l.y + r.y;
    e1 = e1 > 0.f ? e1 : 0.2f * e1;
    alpha[i] = make_float2(e0, e1);
    m0 = fmaxf(m0, e0);
    m1 = fmaxf(m1, e1);
  }
  float s0 = 0.f, s1 = 0.f;
  for (int i = beg; i < end; ++i) {
    float2 a = alpha[i];
    float p0 = __expf(a.x - m0);
    float p1 = __expf(a.y - m1);
    s0 += p0;
    s1 += p1;
    alpha[i] = make_float2(p0, p1);
  }
  inv_s[n] = make_float2(1.0f / fmaxf(s0, 1e-9f), 1.0f / fmaxf(s1, 1e-9f));
}

// ---------------- fused GAT layer 1 aggregation -> h1 bf16 hi/lo -----------
__global__ __launch_bounds__(256) void gat1_agg(const float2* __restrict__ featI,
                                                const float2* __restrict__ alpha,
                                                const float2* __restrict__ inv_s,
                                                const int* __restrict__ row_start,
                                                const int* __restrict__ csr_src,
                                                const float* __restrict__ b,
                                                unsigned short* __restrict__ h1h,
                                                unsigned short* __restrict__ h1l, int N) {
  int wid = threadIdx.x >> 6;
  int lane = threadIdx.x & 63;
  int n = blockIdx.x * 4 + wid;
  if (n >= N) return;
  int beg = row_start[n], end = row_start[n + 1];
  float a0 = 0.f, a1 = 0.f;
  int i = beg;
  for (; i + 1 < end; i += 2) {
    int u0 = csr_src[i], u1 = csr_src[i + 1];
    float2 p0 = alpha[i], p1 = alpha[i + 1];
    float2 f0 = featI[(size_t)u0 * 64 + lane];
    float2 f1 = featI[(size_t)u1 * 64 + lane];
    a0 = fmaf(p0.x, f0.x, a0);
    a1 = fmaf(p0.y, f0.y, a1);
    a0 = fmaf(p1.x, f1.x, a0);
    a1 = fmaf(p1.y, f1.y, a1);
  }
  if (i < end) {
    float2 p = alpha[i];
    float2 f = featI[(size_t)csr_src[i] * 64 + lane];
    a0 = fmaf(p.x, f.x, a0);
    a1 = fmaf(p.y, f.y, a1);
  }
  float2 is = inv_s[n];
  float o0 = elu_f(a0 * is.x + b[lane]);
  float o1 = elu_f(a1 * is.y + b[64 + lane]);
  size_t base = (size_t)n * 128;
  unsigned short hh0 = f2bf(o0), hh1 = f2bf(o1);
  h1h[base + lane] = hh0;
  h1l[base + lane] = f2bf(o0 - bf2f(hh0));
  h1h[base + 64 + lane] = hh1;
  h1l[base + 64 + lane] = f2bf(o1 - bf2f(hh1));
}

// ---------------- per-node attention logits (layer 2) ----------------------
__global__ __launch_bounds__(256) void elr2_kernel(const float* __restrict__ feat,  // ld 48
                                                   const float* __restrict__ al,
                                                   const float* __restrict__ ar,
                                                   float* __restrict__ el,
                                                   float* __restrict__ er, int N) {
  int wid = threadIdx.x >> 6;
  int lane = threadIdx.x & 63;
  int n = blockIdx.x * 4 + wid;
  if (n >= N) return;
  float f = 0.f, a = 0.f, r = 0.f;
  if (lane < 47) {
    f = feat[(size_t)n * 48 + lane];
    a = al[lane];
    r = ar[lane];
  }
  float e = wave_sum(f * a);
  float rr = wave_sum(f * r);
  if (lane == 0) {
    el[n] = e;
    er[n] = rr;
  }
}

// ---------------- attn2: thread per node ----------------------------------
__global__ __launch_bounds__(256) void attn2_kernel(const float* __restrict__ el,
                                                    const float* __restrict__ er,
                                                    const int* __restrict__ row_start,
                                                    const int* __restrict__ csr_src,
                                                    float* __restrict__ alpha,
                                                    float* __restrict__ inv_s, int N) {
  int n = blockIdx.x * 256 + threadIdx.x;
  if (n >= N) return;
  int beg = row_start[n], end = row_start[n + 1];
  float r = er[n];
  float m = -INFINITY;
  for (int i = beg; i < end; ++i) {
    float e = el[csr_src[i]] + r;
    e = e > 0.f ? e : 0.2f * e;
    alpha[i] = e;
    m = fmaxf(m, e);
  }
  float s = 0.f;
  for (int i = beg; i < end; ++i) {
    float p = __expf(alpha[i] - m);
    s += p;
    alpha[i] = p;
  }
  inv_s[n] = 1.0f / fmaxf(s, 1e-9f);
}

// ---------------- fused GAT layer 2 aggregation -> d_out ------------------
__global__ __launch_bounds__(256) void gat2_agg(const float* __restrict__ feat,  // ld 48
                                                const float* __restrict__ alpha,
                                                const float* __restrict__ inv_s,
                                                const int* __restrict__ row_start,
                                                const int* __restrict__ csr_src,
                                                const float* __restrict__ b,
                                                float* __restrict__ out, int N) {
  int wid = threadIdx.x >> 6;
  int lane = threadIdx.x & 63;
  int n = blockIdx.x * 4 + wid;
  if (n >= N) return;
  int beg = row_start[n], end = row_start[n + 1];
  int lidx = lane < 47 ? lane : 0;
  float acc = 0.f;
  int i = beg;
  for (; i + 1 < end; i += 2) {
    int u0 = csr_src[i], u1 = csr_src[i + 1];
    float p0 = alpha[i], p1 = alpha[i + 1];
    acc = fmaf(p0, feat[(size_t)u0 * 48 + lidx], acc);
    acc = fmaf(p1, feat[(size_t)u1 * 48 + lidx], acc);
  }
  if (i < end) {
    acc = fmaf(alpha[i], feat[(size_t)csr_src[i] * 48 + lidx], acc);
  }
  if (lane < 47) {
    out[(size_t)n * 47 + lane] = acc * inv_s[n] + b[lane];
  }
}

// ---------------------------------------------------------------------------
extern "C" void kernel_launch(void* const* d_in, const int* in_sizes, int n_in,
                              void* d_out, int out_size, void* d_ws, size_t ws_size,
                              hipStream_t stream) {
  const float* x = (const float*)d_in[0];
  const int* src = (const int*)d_in[1];
  const int* dst = (const int*)d_in[2];
  const float* sage_w_self = (const float*)d_in[3];
  const float* sage_w_neigh = (const float*)d_in[4];
  const float* sage_b = (const float*)d_in[5];
  const float* gat1_w = (const float*)d_in[6];
  const float* gat1_al = (const float*)d_in[7];
  const float* gat1_ar = (const float*)d_in[8];
  const float* gat1_b = (const float*)d_in[9];
  const float* gat2_w = (const float*)d_in[10];
  const float* gat2_al = (const float*)d_in[11];
  const float* gat2_ar = (const float*)d_in[12];
  const float* gat2_b = (const float*)d_in[13];
  float* out = (float*)d_out;

  const int N = in_sizes[0] / 256;
  const int E = in_sizes[1];

  char* ws = (char*)d_ws;
  size_t off = 0;
  auto alloc = [&](size_t bytes) {
    size_t o = off;
    off += (bytes + 255) & ~(size_t)255;
    return o;
  };
  int* deg_i = (int*)(ws + alloc((size_t)N * 4));
  int* row_start = (int*)(ws + alloc((size_t)(N + 1) * 4));
  int* cursor = (int*)(ws + alloc((size_t)N * 4));
  int* csr_src = (int*)(ws + alloc((size_t)E * 4));
  float* bufA = (float*)(ws + alloc((size_t)N * 128 * 4));   // z -> feat1 -> feat2
  float* bufB = (float*)(ws + alloc((size_t)N * 128 * 4));   // yI -> alpha1 -> alpha2
  unsigned short* bufX = (unsigned short*)(ws + alloc((size_t)N * 256 * 2 * 2));  // xh|xl
  unsigned short* wt_sh = (unsigned short*)(ws + alloc(128 * 256 * 2));
  unsigned short* wt_sl = (unsigned short*)(ws + alloc(128 * 256 * 2));
  unsigned short* wt_nh = (unsigned short*)(ws + alloc(128 * 256 * 2));
  unsigned short* wt_nl = (unsigned short*)(ws + alloc(128 * 256 * 2));
  unsigned short* wt_1h = (unsigned short*)(ws + alloc(128 * 128 * 2));
  unsigned short* wt_1l = (unsigned short*)(ws + alloc(128 * 128 * 2));
  unsigned short* wt_2h = (unsigned short*)(ws + alloc(48 * 128 * 2));
  unsigned short* wt_2l = (unsigned short*)(ws + alloc(48 * 128 * 2));
  float2* el1 = (float2*)(ws + alloc((size_t)N * 8));
  float2* er1 = (float2*)(ws + alloc((size_t)N * 8));
  float* el2 = (float*)(ws + alloc((size_t)N * 4));
  float* er2 = (float*)(ws + alloc((size_t)N * 4));
  float2* inv_s1 = (float2*)(ws + alloc((size_t)N * 8));
  float* inv_s2 = (float*)(ws + alloc((size_t)N * 4));
  (void)ws_size;
  (void)n_in;
  (void)out_size;

  // lifetimes:
  unsigned short* xh = bufX;                        // dead after L0 gemm
  unsigned short* xl = bufX + (size_t)N * 256;      // dead after L0 gemm
  float* z = bufA;
  float* yI = bufB;
  unsigned short* h0h = bufX;                       // reuse xh region
  unsigned short* h0l = bufX + (size_t)N * 128;
  float* feat1 = bufA;
  float2* alpha1 = (float2*)bufB;
  unsigned short* h1h = bufX + (size_t)N * 256;     // reuse xl region
  unsigned short* h1l = bufX + (size_t)N * 256 + (size_t)N * 128;
  float* feat2 = bufA;  // ld 48
  float* alpha2 = bufB;

  hipMemsetAsync(deg_i, 0, (size_t)N * 4, stream);
  hipMemsetAsync(cursor, 0, (size_t)N * 4, stream);

  const int eb = (E + 255) / 256;
  const int nb4 = (N + 3) / 4;
  const int nb256 = (N + 255) / 256;
  const int gx = (N + 127) / 128;  // 128-row blocks for gemm_mfma

  // prep: split x, transpose+split weights
  split_x<<<2048, 256, 0, stream>>>(x, xh, xl, N * 64);
  prep_w<<<(128 * 256 + 255) / 256, 256, 0, stream>>>(sage_w_self, 128, 256, 128, wt_sh, wt_sl);
  prep_w<<<(128 * 256 + 255) / 256, 256, 0, stream>>>(sage_w_neigh, 128, 256, 128, wt_nh, wt_nl);
  prep_w<<<(128 * 128 + 255) / 256, 256, 0, stream>>>(gat1_w, 128, 128, 128, wt_1h, wt_1l);
  prep_w<<<(48 * 128 + 255) / 256, 256, 0, stream>>>(gat2_w, 47, 128, 48, wt_2h, wt_2l);

  deg_kernel<<<eb, 256, 0, stream>>>(dst, deg_i, E);
  scan_kernel<<<1, 1024, 0, stream>>>(deg_i, row_start, N);
  scatter_kernel<<<eb, 256, 0, stream>>>(src, dst, row_start, cursor, csr_src, E);

  // layer 0: y=0 -> z = x@W_self (std), y=1 -> yI = x@W_neigh (ilv)
  {
    dim3 grid(gx, 2);
    gemm_mfma<256, 8><<<grid, 256, 0, stream>>>(xh, xl, wt_sh, wt_sl, wt_nh, wt_nl,
                                                z, yI, 128, N, 128, 0, 1);
  }
  sage_agg<<<nb4, 256, 0, stream>>>(z, (const float2*)yI, row_start, csr_src, sage_b,
                                    h0h, h0l, N);

  // GAT layer 1: feat1 = h0 @ gat1_w (interleaved)
  {
    dim3 grid(gx, 1);
    gemm_mfma<128, 8><<<grid, 256, 0, stream>>>(h0h, h0l, wt_1h, wt_1l, wt_1h, wt_1l,
                                                feat1, feat1, 128, N, 128, 1, 1);
  }
  elr1_kernel<<<nb4, 256, 0, stream>>>((const float2*)feat1, gat1_al, gat1_ar, el1, er1, N);
  attn1_kernel<<<nb256, 256, 0, stream>>>(el1, er1, row_start, csr_src, alpha1, inv_s1, N);
  gat1_agg<<<nb4, 256, 0, stream>>>((const float2*)feat1, alpha1, inv_s1, row_start,
                                    csr_src, gat1_b, h1h, h1l, N);

  // GAT layer 2: feat2 = h1 @ gat2_w (ld 48, Ncols=47)
  {
    dim3 grid(gx, 1);
    gemm_mfma<128, 3><<<grid, 256, 0, stream>>>(h1h, h1l, wt_2h, wt_2l, wt_2h, wt_2l,
                                                feat2, feat2, 48, N, 47, 0, 0);
  }
  elr2_kernel<<<nb4, 256, 0, stream>>>(feat2, gat2_al, gat2_ar, el2, er2, N);
  attn2_kernel<<<nb256, 256, 0, stream>>>(el2, er2, row_start, csr_src, alpha2, inv_s2, N);
  gat2_agg<<<nb4, 256, 0, stream>>>(feat2, alpha2, inv_s2, row_start, csr_src, gat2_b, out, N);
}

// Round 7
// 475.110 us; speedup vs baseline: 1.7027x; 1.1076x over previous
//
#include <hip/hip_runtime.h>

// ---------------------------------------------------------------------------
// GAT_4733053960619: SAGEConv(mean) -> ELU -> GAT(2 heads,64) -> ELU -> GAT(1,47)
// N=50000, E=800000, IN_FEATS=256. All fp32.
//
// R6: gemm_mfma B-operand staged in LDS (m97 structure). R5 was VMEM-latency
// bound (MfmaUtil 8.5%): every wave privately re-read B^T from L2. Now the
// block stages each kt-slice of B^T hi/lo into LDS in FRAGMENT ORDER via
// global_load_lds (per-lane global src, linear LDS dest), double-buffered,
// one barrier per kt. Compute reads are base+lane*16 (even bank spread).
// A keeps direct per-lane loads + register prefetch (A has no reuse).
// ---------------------------------------------------------------------------

typedef __attribute__((ext_vector_type(8))) short bf16x8;
typedef __attribute__((ext_vector_type(4))) float f32x4;

__device__ __forceinline__ float wave_sum(float v) {
#pragma unroll
  for (int o = 32; o > 0; o >>= 1) v += __shfl_xor(v, o, 64);
  return v;
}

__device__ __forceinline__ float elu_f(float v) {
  return v > 0.f ? v : __expf(v) - 1.0f;
}

__device__ __forceinline__ unsigned short f2bf(float x) {
  union { float f; unsigned u; } v;
  v.f = x;
  unsigned r = v.u + 0x7FFFu + ((v.u >> 16) & 1u);
  return (unsigned short)(r >> 16);
}

__device__ __forceinline__ float bf2f(unsigned short h) {
  union { unsigned u; float f; } v;
  v.u = ((unsigned)h) << 16;
  return v.f;
}

// ---------------- CSR build ----------------
__global__ __launch_bounds__(256) void deg_kernel(const int* __restrict__ dst,
                                                  int* __restrict__ deg, int E) {
  int i = blockIdx.x * 256 + threadIdx.x;
  if (i < E) atomicAdd(&deg[dst[i]], 1);
}

__global__ __launch_bounds__(1024) void scan_kernel(const int* __restrict__ deg,
                                                    int* __restrict__ row_start, int n) {
  __shared__ int wsum[16];
  __shared__ int wpre[16];
  __shared__ int s_carry;
  const int t = threadIdx.x;
  const int lane = t & 63;
  const int w = t >> 6;
  if (t == 0) s_carry = 0;
  __syncthreads();
  for (int base = 0; base < n; base += 1024) {
    int v = (base + t < n) ? deg[base + t] : 0;
    int inc = v;
#pragma unroll
    for (int o = 1; o < 64; o <<= 1) {
      int u = __shfl_up(inc, o, 64);
      if (lane >= o) inc += u;
    }
    if (lane == 63) wsum[w] = inc;
    __syncthreads();
    if (w == 0 && lane < 16) {
      int s = wsum[lane];
      int p = s;
#pragma unroll
      for (int o = 1; o < 16; o <<= 1) {
        int u = __shfl_up(p, o, 64);
        if (lane >= o) p += u;
      }
      wpre[lane] = p - s;
    }
    __syncthreads();
    int carry = s_carry;
    if (base + t < n) row_start[base + t] = carry + wpre[w] + inc - v;
    __syncthreads();
    if (t == 1023) s_carry = carry + wpre[15] + inc;
    __syncthreads();
  }
  if (t == 0) row_start[n] = s_carry;
}

__global__ __launch_bounds__(256) void scatter_kernel(const int* __restrict__ src,
                                                      const int* __restrict__ dst,
                                                      const int* __restrict__ row_start,
                                                      int* __restrict__ cursor,
                                                      int* __restrict__ csr_src, int E) {
  int i = blockIdx.x * 256 + threadIdx.x;
  if (i < E) {
    int d = dst[i];
    int p = atomicAdd(&cursor[d], 1);
    csr_src[row_start[d] + p] = src[i];
  }
}

// ---------------- fp32 -> bf16 hi/lo split (x input) ----------------
__global__ __launch_bounds__(256) void split_x(const float* __restrict__ x,
                                               unsigned short* __restrict__ xh,
                                               unsigned short* __restrict__ xl, int n4) {
  int i = blockIdx.x * 256 + threadIdx.x;
  int stride = gridDim.x * 256;
  for (; i < n4; i += stride) {
    float4 v = ((const float4*)x)[i];
    ushort4 h, l;
    h.x = f2bf(v.x); l.x = f2bf(v.x - bf2f(h.x));
    h.y = f2bf(v.y); l.y = f2bf(v.y - bf2f(h.y));
    h.z = f2bf(v.z); l.z = f2bf(v.z - bf2f(h.z));
    h.w = f2bf(v.w); l.w = f2bf(v.w - bf2f(h.w));
    ((ushort4*)xh)[i] = h;
    ((ushort4*)xl)[i] = l;
  }
}

// ---------------- weight prep: W[K][N] f32 -> W^T hi/lo [Npad][K] bf16 ------
__global__ __launch_bounds__(256) void prep_w(const float* __restrict__ W, int N, int K,
                                              int Npad, unsigned short* __restrict__ th,
                                              unsigned short* __restrict__ tl) {
  int i = blockIdx.x * 256 + threadIdx.x;
  if (i >= Npad * K) return;
  int n = i / K, k = i - n * K;
  float v = (n < N) ? W[(size_t)k * N + n] : 0.f;
  unsigned short h = f2bf(v);
  th[i] = h;
  tl[i] = f2bf(v - bf2f(h));
}

// ---------------- MFMA GEMM: C[M,Ncols] = A @ B, split-bf16, LDS-staged B --
// A as hi/lo bf16 [M][K]; B^T as hi/lo bf16 [Npad][K]; Npad = NT*16.
// Block = 4 waves = 128 rows; wave = 32 rows (2 fragments) x NT*16 cols.
// LDS: per kt-slice, fragment-order layout: region nt holds 64 chunks of 16B
// at (kg*16+lrow)*16B = B^T row (nt*16+lrow), elems [kt*32+kg*8, +8).
// Staged by global_load_lds (per-lane global src, linear LDS dest).
// blockIdx.y picks {BT0,C0,ilv0} / {BT1,C1,ilv1}.
// ilv: logical col gc stored at (gc&63)*2+(gc>>6)  (head-interleave, Ncols=128).
template <int K, int NT>
__global__ __launch_bounds__(256) void gemm_mfma(
    const unsigned short* __restrict__ Ah, const unsigned short* __restrict__ Al,
    const unsigned short* __restrict__ BTh0, const unsigned short* __restrict__ BTl0,
    const unsigned short* __restrict__ BTh1, const unsigned short* __restrict__ BTl1,
    float* __restrict__ C0, float* __restrict__ C1,
    int ldc, int M, int Ncols, int ilv0, int ilv1) {
  constexpr int K2 = K * 2;    // bytes per B^T row
  constexpr int NKT = K / 32;  // k-tiles
  __shared__ unsigned short Bs[2][2][NT * 512];  // [buf][hi/lo][nt*512 + kg*128 + lrow*8]

  const unsigned short* BTh = blockIdx.y ? BTh1 : BTh0;
  const unsigned short* BTl = blockIdx.y ? BTl1 : BTl0;
  float* C = blockIdx.y ? C1 : C0;
  const int ilv = blockIdx.y ? ilv1 : ilv0;

  const int wid = threadIdx.x >> 6;
  const int lane = threadIdx.x & 63;
  const int lrow = lane & 15;
  const int kg = lane >> 4;
  const int row0 = blockIdx.x * 128 + wid * 32;
  const int ra = min(row0 + lrow, M - 1);
  const int rb = min(row0 + 16 + lrow, M - 1);
  const size_t aoffA = (size_t)ra * K + kg * 8;
  const size_t aoffB = (size_t)rb * K + kg * 8;

  // stage kt-slice of B^T (hi and lo) into Bs[buf]
  auto stage = [&](int buf, int kt) {
    for (int j = wid; j < 2 * NT; j += 4) {
      const int h = (j >= NT) ? 1 : 0;
      const int nt = h ? j - NT : j;
      const unsigned short* src = h ? BTl : BTh;
      const char* g = (const char*)src + (size_t)(nt * 16 + lrow) * K2 + kt * 64 + kg * 16;
      unsigned short* l = &Bs[buf][h][nt * 512];
      __builtin_amdgcn_global_load_lds(
          (const __attribute__((address_space(1))) unsigned*)g,
          (__attribute__((address_space(3))) unsigned*)l, 16, 0, 0);
    }
  };

  f32x4 accA[NT] = {};
  f32x4 accB[NT] = {};

  stage(0, 0);
  bf16x8 cahA = *(const bf16x8*)(Ah + aoffA);
  bf16x8 calA = *(const bf16x8*)(Al + aoffA);
  bf16x8 cahB = *(const bf16x8*)(Ah + aoffB);
  bf16x8 calB = *(const bf16x8*)(Al + aoffB);

  for (int kt = 0; kt < NKT; ++kt) {
    __syncthreads();  // buf[kt&1] staged (drains vmcnt+lgkmcnt)
    if (kt + 1 < NKT) stage((kt + 1) & 1, kt + 1);
    const int kn = (kt + 1 < NKT) ? (kt + 1) * 32 : kt * 32;
    bf16x8 nahA = *(const bf16x8*)(Ah + aoffA + kn);
    bf16x8 nalA = *(const bf16x8*)(Al + aoffA + kn);
    bf16x8 nahB = *(const bf16x8*)(Ah + aoffB + kn);
    bf16x8 nalB = *(const bf16x8*)(Al + aoffB + kn);
    const int buf = kt & 1;
#pragma unroll
    for (int nt = 0; nt < NT; ++nt) {
      bf16x8 bh = ((const bf16x8*)&Bs[buf][0][nt * 512])[lane];
      bf16x8 bl = ((const bf16x8*)&Bs[buf][1][nt * 512])[lane];
      accA[nt] = __builtin_amdgcn_mfma_f32_16x16x32_bf16(cahA, bh, accA[nt], 0, 0, 0);
      accA[nt] = __builtin_amdgcn_mfma_f32_16x16x32_bf16(cahA, bl, accA[nt], 0, 0, 0);
      accA[nt] = __builtin_amdgcn_mfma_f32_16x16x32_bf16(calA, bh, accA[nt], 0, 0, 0);
      accB[nt] = __builtin_amdgcn_mfma_f32_16x16x32_bf16(cahB, bh, accB[nt], 0, 0, 0);
      accB[nt] = __builtin_amdgcn_mfma_f32_16x16x32_bf16(cahB, bl, accB[nt], 0, 0, 0);
      accB[nt] = __builtin_amdgcn_mfma_f32_16x16x32_bf16(calB, bh, accB[nt], 0, 0, 0);
    }
    cahA = nahA; calA = nalA; cahB = nahB; calB = nalB;
  }

#pragma unroll
  for (int nt = 0; nt < NT; ++nt) {
    int gc = nt * 16 + lrow;
    if (gc >= Ncols) continue;
    int oc = ilv ? ((gc & 63) * 2 + (gc >> 6)) : gc;
#pragma unroll
    for (int r = 0; r < 4; ++r) {
      int g0 = row0 + kg * 4 + r;
      if (g0 < M) C[(size_t)g0 * ldc + oc] = accA[nt][r];
      int g1 = row0 + 16 + kg * 4 + r;
      if (g1 < M) C[(size_t)g1 * ldc + oc] = accB[nt][r];
    }
  }
}

// ---------------- SAGE aggregation (wave per node) -> h0 bf16 hi/lo --------
__global__ __launch_bounds__(256) void sage_agg(const float* __restrict__ z,
                                                const float2* __restrict__ yI,
                                                const int* __restrict__ row_start,
                                                const int* __restrict__ csr_src,
                                                const float* __restrict__ b,
                                                unsigned short* __restrict__ h0h,
                                                unsigned short* __restrict__ h0l, int N) {
  int wid = threadIdx.x >> 6;
  int lane = threadIdx.x & 63;
  int n = blockIdx.x * 4 + wid;
  if (n >= N) return;
  int s = row_start[n], e = row_start[n + 1];
  float a0 = 0.f, a1 = 0.f;
  int i = s;
  for (; i + 1 < e; i += 2) {
    int u0 = csr_src[i], u1 = csr_src[i + 1];
    float2 f0 = yI[(size_t)u0 * 64 + lane];
    float2 f1 = yI[(size_t)u1 * 64 + lane];
    a0 += f0.x + f1.x;
    a1 += f0.y + f1.y;
  }
  if (i < e) {
    float2 f = yI[(size_t)csr_src[i] * 64 + lane];
    a0 += f.x;
    a1 += f.y;
  }
  float inv = 1.0f / fmaxf((float)(e - s), 1.0f);
  size_t base = (size_t)n * 128;
  float v0 = elu_f(z[base + lane] + a0 * inv + b[lane]);
  float v1 = elu_f(z[base + 64 + lane] + a1 * inv + b[64 + lane]);
  unsigned short hh0 = f2bf(v0), hh1 = f2bf(v1);
  h0h[base + lane] = hh0;
  h0l[base + lane] = f2bf(v0 - bf2f(hh0));
  h0h[base + 64 + lane] = hh1;
  h0l[base + 64 + lane] = f2bf(v1 - bf2f(hh1));
}

// ---------------- per-node attention logits (layer 1) ----------------------
__global__ __launch_bounds__(256) void elr1_kernel(const float2* __restrict__ featI,
                                                   const float* __restrict__ al,
                                                   const float* __restrict__ ar,
                                                   float2* __restrict__ el,
                                                   float2* __restrict__ er, int N) {
  int wid = threadIdx.x >> 6;
  int lane = threadIdx.x & 63;
  int n = blockIdx.x * 4 + wid;
  if (n >= N) return;
  float2 f = featI[(size_t)n * 64 + lane];
  float e0 = wave_sum(f.x * al[lane]);
  float e1 = wave_sum(f.y * al[64 + lane]);
  float r0 = wave_sum(f.x * ar[lane]);
  float r1 = wave_sum(f.y * ar[64 + lane]);
  if (lane == 0) {
    el[n] = make_float2(e0, e1);
    er[n] = make_float2(r0, r1);
  }
}

// ---------------- attn1: thread per node, softmax weights ------------------
__global__ __launch_bounds__(256) void attn1_kernel(const float2* __restrict__ el,
                                                    const float2* __restrict__ er,
                                                    const int* __restrict__ row_start,
                                                    const int* __restrict__ csr_src,
                                                    float2* __restrict__ alpha,
                                                    float2* __restrict__ inv_s, int N) {
  int n = blockIdx.x * 256 + threadIdx.x;
  if (n >= N) return;
  int beg = row_start[n], end = row_start[n + 1];
  float2 r = er[n];
  float m0 = -INFINITY, m1 = -INFINITY;
  for (int i = beg; i < end; ++i) {
    float2 l = el[csr_src[i]];
    float e0 = l.x + r.x;
    e0 = e0 > 0.f ? e0 : 0.2f * e0;
    float e1 = l.y + r.y;
    e1 = e1 > 0.f ? e1 : 0.2f * e1;
    alpha[i] = make_float2(e0, e1);
    m0 = fmaxf(m0, e0);
    m1 = fmaxf(m1, e1);
  }
  float s0 = 0.f, s1 = 0.f;
  for (int i = beg; i < end; ++i) {
    float2 a = alpha[i];
    float p0 = __expf(a.x - m0);
    float p1 = __expf(a.y - m1);
    s0 += p0;
    s1 += p1;
    alpha[i] = make_float2(p0, p1);
  }
  inv_s[n] = make_float2(1.0f / fmaxf(s0, 1e-9f), 1.0f / fmaxf(s1, 1e-9f));
}

// ---------------- fused GAT layer 1 aggregation -> h1 bf16 hi/lo -----------
__global__ __launch_bounds__(256) void gat1_agg(const float2* __restrict__ featI,
                                                const float2* __restrict__ alpha,
                                                const float2* __restrict__ inv_s,
                                                const int* __restrict__ row_start,
                                                const int* __restrict__ csr_src,
                                                const float* __restrict__ b,
                                                unsigned short* __restrict__ h1h,
                                                unsigned short* __restrict__ h1l, int N) {
  int wid = threadIdx.x >> 6;
  int lane = threadIdx.x & 63;
  int n = blockIdx.x * 4 + wid;
  if (n >= N) return;
  int beg = row_start[n], end = row_start[n + 1];
  float a0 = 0.f, a1 = 0.f;
  int i = beg;
  for (; i + 1 < end; i += 2) {
    int u0 = csr_src[i], u1 = csr_src[i + 1];
    float2 p0 = alpha[i], p1 = alpha[i + 1];
    float2 f0 = featI[(size_t)u0 * 64 + lane];
    float2 f1 = featI[(size_t)u1 * 64 + lane];
    a0 = fmaf(p0.x, f0.x, a0);
    a1 = fmaf(p0.y, f0.y, a1);
    a0 = fmaf(p1.x, f1.x, a0);
    a1 = fmaf(p1.y, f1.y, a1);
  }
  if (i < end) {
    float2 p = alpha[i];
    float2 f = featI[(size_t)csr_src[i] * 64 + lane];
    a0 = fmaf(p.x, f.x, a0);
    a1 = fmaf(p.y, f.y, a1);
  }
  float2 is = inv_s[n];
  float o0 = elu_f(a0 * is.x + b[lane]);
  float o1 = elu_f(a1 * is.y + b[64 + lane]);
  size_t base = (size_t)n * 128;
  unsigned short hh0 = f2bf(o0), hh1 = f2bf(o1);
  h1h[base + lane] = hh0;
  h1l[base + lane] = f2bf(o0 - bf2f(hh0));
  h1h[base + 64 + lane] = hh1;
  h1l[base + 64 + lane] = f2bf(o1 - bf2f(hh1));
}

// ---------------- per-node attention logits (layer 2) ----------------------
__global__ __launch_bounds__(256) void elr2_kernel(const float* __restrict__ feat,  // ld 48
                                                   const float* __restrict__ al,
                                                   const float* __restrict__ ar,
                                                   float* __restrict__ el,
                                                   float* __restrict__ er, int N) {
  int wid = threadIdx.x >> 6;
  int lane = threadIdx.x & 63;
  int n = blockIdx.x * 4 + wid;
  if (n >= N) return;
  float f = 0.f, a = 0.f, r = 0.f;
  if (lane < 47) {
    f = feat[(size_t)n * 48 + lane];
    a = al[lane];
    r = ar[lane];
  }
  float e = wave_sum(f * a);
  float rr = wave_sum(f * r);
  if (lane == 0) {
    el[n] = e;
    er[n] = rr;
  }
}

// ---------------- attn2: thread per node ----------------------------------
__global__ __launch_bounds__(256) void attn2_kernel(const float* __restrict__ el,
                                                    const float* __restrict__ er,
                                                    const int* __restrict__ row_start,
                                                    const int* __restrict__ csr_src,
                                                    float* __restrict__ alpha,
                                                    float* __restrict__ inv_s, int N) {
  int n = blockIdx.x * 256 + threadIdx.x;
  if (n >= N) return;
  int beg = row_start[n], end = row_start[n + 1];
  float r = er[n];
  float m = -INFINITY;
  for (int i = beg; i < end; ++i) {
    float e = el[csr_src[i]] + r;
    e = e > 0.f ? e : 0.2f * e;
    alpha[i] = e;
    m = fmaxf(m, e);
  }
  float s = 0.f;
  for (int i = beg; i < end; ++i) {
    float p = __expf(alpha[i] - m);
    s += p;
    alpha[i] = p;
  }
  inv_s[n] = 1.0f / fmaxf(s, 1e-9f);
}

// ---------------- fused GAT layer 2 aggregation -> d_out ------------------
__global__ __launch_bounds__(256) void gat2_agg(const float* __restrict__ feat,  // ld 48
                                                const float* __restrict__ alpha,
                                                const float* __restrict__ inv_s,
                                                const int* __restrict__ row_start,
                                                const int* __restrict__ csr_src,
                                                const float* __restrict__ b,
                                                float* __restrict__ out, int N) {
  int wid = threadIdx.x >> 6;
  int lane = threadIdx.x & 63;
  int n = blockIdx.x * 4 + wid;
  if (n >= N) return;
  int beg = row_start[n], end = row_start[n + 1];
  int lidx = lane < 47 ? lane : 0;
  float acc = 0.f;
  int i = beg;
  for (; i + 1 < end; i += 2) {
    int u0 = csr_src[i], u1 = csr_src[i + 1];
    float p0 = alpha[i], p1 = alpha[i + 1];
    acc = fmaf(p0, feat[(size_t)u0 * 48 + lidx], acc);
    acc = fmaf(p1, feat[(size_t)u1 * 48 + lidx], acc);
  }
  if (i < end) {
    acc = fmaf(alpha[i], feat[(size_t)csr_src[i] * 48 + lidx], acc);
  }
  if (lane < 47) {
    out[(size_t)n * 47 + lane] = acc * inv_s[n] + b[lane];
  }
}

// ---------------------------------------------------------------------------
extern "C" void kernel_launch(void* const* d_in, const int* in_sizes, int n_in,
                              void* d_out, int out_size, void* d_ws, size_t ws_size,
                              hipStream_t stream) {
  const float* x = (const float*)d_in[0];
  const int* src = (const int*)d_in[1];
  const int* dst = (const int*)d_in[2];
  const float* sage_w_self = (const float*)d_in[3];
  const float* sage_w_neigh = (const float*)d_in[4];
  const float* sage_b = (const float*)d_in[5];
  const float* gat1_w = (const float*)d_in[6];
  const float* gat1_al = (const float*)d_in[7];
  const float* gat1_ar = (const float*)d_in[8];
  const float* gat1_b = (const float*)d_in[9];
  const float* gat2_w = (const float*)d_in[10];
  const float* gat2_al = (const float*)d_in[11];
  const float* gat2_ar = (const float*)d_in[12];
  const float* gat2_b = (const float*)d_in[13];
  float* out = (float*)d_out;

  const int N = in_sizes[0] / 256;
  const int E = in_sizes[1];

  char* ws = (char*)d_ws;
  size_t off = 0;
  auto alloc = [&](size_t bytes) {
    size_t o = off;
    off += (bytes + 255) & ~(size_t)255;
    return o;
  };
  int* deg_i = (int*)(ws + alloc((size_t)N * 4));
  int* row_start = (int*)(ws + alloc((size_t)(N + 1) * 4));
  int* cursor = (int*)(ws + alloc((size_t)N * 4));
  int* csr_src = (int*)(ws + alloc((size_t)E * 4));
  float* bufA = (float*)(ws + alloc((size_t)N * 128 * 4));   // z -> feat1 -> feat2
  float* bufB = (float*)(ws + alloc((size_t)N * 128 * 4));   // yI -> alpha1 -> alpha2
  unsigned short* bufX = (unsigned short*)(ws + alloc((size_t)N * 256 * 2 * 2));  // xh|xl
  unsigned short* wt_sh = (unsigned short*)(ws + alloc(128 * 256 * 2));
  unsigned short* wt_sl = (unsigned short*)(ws + alloc(128 * 256 * 2));
  unsigned short* wt_nh = (unsigned short*)(ws + alloc(128 * 256 * 2));
  unsigned short* wt_nl = (unsigned short*)(ws + alloc(128 * 256 * 2));
  unsigned short* wt_1h = (unsigned short*)(ws + alloc(128 * 128 * 2));
  unsigned short* wt_1l = (unsigned short*)(ws + alloc(128 * 128 * 2));
  unsigned short* wt_2h = (unsigned short*)(ws + alloc(48 * 128 * 2));
  unsigned short* wt_2l = (unsigned short*)(ws + alloc(48 * 128 * 2));
  float2* el1 = (float2*)(ws + alloc((size_t)N * 8));
  float2* er1 = (float2*)(ws + alloc((size_t)N * 8));
  float* el2 = (float*)(ws + alloc((size_t)N * 4));
  float* er2 = (float*)(ws + alloc((size_t)N * 4));
  float2* inv_s1 = (float2*)(ws + alloc((size_t)N * 8));
  float* inv_s2 = (float*)(ws + alloc((size_t)N * 4));
  (void)ws_size;
  (void)n_in;
  (void)out_size;

  // lifetimes:
  unsigned short* xh = bufX;                        // dead after L0 gemm
  unsigned short* xl = bufX + (size_t)N * 256;      // dead after L0 gemm
  float* z = bufA;
  float* yI = bufB;
  unsigned short* h0h = bufX;                       // reuse xh region
  unsigned short* h0l = bufX + (size_t)N * 128;
  float* feat1 = bufA;
  float2* alpha1 = (float2*)bufB;
  unsigned short* h1h = bufX + (size_t)N * 256;     // reuse xl region
  unsigned short* h1l = bufX + (size_t)N * 256 + (size_t)N * 128;
  float* feat2 = bufA;  // ld 48
  float* alpha2 = bufB;

  hipMemsetAsync(deg_i, 0, (size_t)N * 4, stream);
  hipMemsetAsync(cursor, 0, (size_t)N * 4, stream);

  const int eb = (E + 255) / 256;
  const int nb4 = (N + 3) / 4;
  const int nb256 = (N + 255) / 256;
  const int gx = (N + 127) / 128;  // 128-row blocks for gemm_mfma

  // prep: split x, transpose+split weights
  split_x<<<2048, 256, 0, stream>>>(x, xh, xl, N * 64);
  prep_w<<<(128 * 256 + 255) / 256, 256, 0, stream>>>(sage_w_self, 128, 256, 128, wt_sh, wt_sl);
  prep_w<<<(128 * 256 + 255) / 256, 256, 0, stream>>>(sage_w_neigh, 128, 256, 128, wt_nh, wt_nl);
  prep_w<<<(128 * 128 + 255) / 256, 256, 0, stream>>>(gat1_w, 128, 128, 128, wt_1h, wt_1l);
  prep_w<<<(48 * 128 + 255) / 256, 256, 0, stream>>>(gat2_w, 47, 128, 48, wt_2h, wt_2l);

  deg_kernel<<<eb, 256, 0, stream>>>(dst, deg_i, E);
  scan_kernel<<<1, 1024, 0, stream>>>(deg_i, row_start, N);
  scatter_kernel<<<eb, 256, 0, stream>>>(src, dst, row_start, cursor, csr_src, E);

  // layer 0: y=0 -> z = x@W_self (std), y=1 -> yI = x@W_neigh (ilv)
  {
    dim3 grid(gx, 2);
    gemm_mfma<256, 8><<<grid, 256, 0, stream>>>(xh, xl, wt_sh, wt_sl, wt_nh, wt_nl,
                                                z, yI, 128, N, 128, 0, 1);
  }
  sage_agg<<<nb4, 256, 0, stream>>>(z, (const float2*)yI, row_start, csr_src, sage_b,
                                    h0h, h0l, N);

  // GAT layer 1: feat1 = h0 @ gat1_w (interleaved)
  {
    dim3 grid(gx, 1);
    gemm_mfma<128, 8><<<grid, 256, 0, stream>>>(h0h, h0l, wt_1h, wt_1l, wt_1h, wt_1l,
                                                feat1, feat1, 128, N, 128, 1, 1);
  }
  elr1_kernel<<<nb4, 256, 0, stream>>>((const float2*)feat1, gat1_al, gat1_ar, el1, er1, N);
  attn1_kernel<<<nb256, 256, 0, stream>>>(el1, er1, row_start, csr_src, alpha1, inv_s1, N);
  gat1_agg<<<nb4, 256, 0, stream>>>((const float2*)feat1, alpha1, inv_s1, row_start,
                                    csr_src, gat1_b, h1h, h1l, N);

  // GAT layer 2: feat2 = h1 @ gat2_w (ld 48, Ncols=47)
  {
    dim3 grid(gx, 1);
    gemm_mfma<128, 3><<<grid, 256, 0, stream>>>(h1h, h1l, wt_2h, wt_2l, wt_2h, wt_2l,
                                                feat2, feat2, 48, N, 47, 0, 0);
  }
  elr2_kernel<<<nb4, 256, 0, stream>>>(feat2, gat2_al, gat2_ar, el2, er2, N);
  attn2_kernel<<<nb256, 256, 0, stream>>>(el2, er2, row_start, csr_src, alpha2, inv_s2, N);
  gat2_agg<<<nb4, 256, 0, stream>>>(feat2, alpha2, inv_s2, row_start, csr_src, gat2_b, out, N);
}

// Round 9
// 444.419 us; speedup vs baseline: 1.8203x; 1.0691x over previous
//
#include <hip/hip_runtime.h>

// ---------------------------------------------------------------------------
// GAT_4733053960619: SAGEConv(mean) -> ELU -> GAT(2 heads,64) -> ELU -> GAT(1,47)
// N=50000, E=800000, IN_FEATS=256. All fp32.
//
// R8 = R7 (bf16 gather tables) with the omode-1 stride bug FIXED:
// packed-bf16 epilogue uses ldu = ldc>>1 uints per row (caller passes the
// f32-equivalent ldc). R7 shipped without this -> yI written at 2x stride,
// sage_agg read garbage (absmax 3.5e-2). Gather tables: yI/feat1I packed
// 2-head bf16 uints (12.8MB), feat2 bf16 ld48 (4.8MB, fits per-XCD L2).
// GEMM-input precision (split-bf16 hi/lo) unchanged.
// ---------------------------------------------------------------------------

typedef __attribute__((ext_vector_type(8))) short bf16x8;
typedef __attribute__((ext_vector_type(4))) float f32x4;

__device__ __forceinline__ float wave_sum(float v) {
#pragma unroll
  for (int o = 32; o > 0; o >>= 1) v += __shfl_xor(v, o, 64);
  return v;
}

__device__ __forceinline__ float elu_f(float v) {
  return v > 0.f ? v : __expf(v) - 1.0f;
}

__device__ __forceinline__ unsigned short f2bf(float x) {
  union { float f; unsigned u; } v;
  v.f = x;
  unsigned r = v.u + 0x7FFFu + ((v.u >> 16) & 1u);
  return (unsigned short)(r >> 16);
}

__device__ __forceinline__ float bf2f(unsigned short h) {
  union { unsigned u; float f; } v;
  v.u = ((unsigned)h) << 16;
  return v.f;
}

// packed 2xbf16 (lo=head0, hi=head1) -> (f0, f1)
__device__ __forceinline__ float2 unpk(unsigned v) {
  union { unsigned u; float f; } a, b;
  a.u = v << 16;
  b.u = v & 0xFFFF0000u;
  return make_float2(a.f, b.f);
}

// ---------------- CSR build ----------------
__global__ __launch_bounds__(256) void deg_kernel(const int* __restrict__ dst,
                                                  int* __restrict__ deg, int E) {
  int i = blockIdx.x * 256 + threadIdx.x;
  if (i < E) atomicAdd(&deg[dst[i]], 1);
}

__global__ __launch_bounds__(1024) void scan_kernel(const int* __restrict__ deg,
                                                    int* __restrict__ row_start, int n) {
  __shared__ int wsum[16];
  __shared__ int wpre[16];
  __shared__ int s_carry;
  const int t = threadIdx.x;
  const int lane = t & 63;
  const int w = t >> 6;
  if (t == 0) s_carry = 0;
  __syncthreads();
  for (int base = 0; base < n; base += 1024) {
    int v = (base + t < n) ? deg[base + t] : 0;
    int inc = v;
#pragma unroll
    for (int o = 1; o < 64; o <<= 1) {
      int u = __shfl_up(inc, o, 64);
      if (lane >= o) inc += u;
    }
    if (lane == 63) wsum[w] = inc;
    __syncthreads();
    if (w == 0 && lane < 16) {
      int s = wsum[lane];
      int p = s;
#pragma unroll
      for (int o = 1; o < 16; o <<= 1) {
        int u = __shfl_up(p, o, 64);
        if (lane >= o) p += u;
      }
      wpre[lane] = p - s;
    }
    __syncthreads();
    int carry = s_carry;
    if (base + t < n) row_start[base + t] = carry + wpre[w] + inc - v;
    __syncthreads();
    if (t == 1023) s_carry = carry + wpre[15] + inc;
    __syncthreads();
  }
  if (t == 0) row_start[n] = s_carry;
}

__global__ __launch_bounds__(256) void scatter_kernel(const int* __restrict__ src,
                                                      const int* __restrict__ dst,
                                                      const int* __restrict__ row_start,
                                                      int* __restrict__ cursor,
                                                      int* __restrict__ csr_src, int E) {
  int i = blockIdx.x * 256 + threadIdx.x;
  if (i < E) {
    int d = dst[i];
    int p = atomicAdd(&cursor[d], 1);
    csr_src[row_start[d] + p] = src[i];
  }
}

// ---------------- fp32 -> bf16 hi/lo split (x input) ----------------
__global__ __launch_bounds__(256) void split_x(const float* __restrict__ x,
                                               unsigned short* __restrict__ xh,
                                               unsigned short* __restrict__ xl, int n4) {
  int i = blockIdx.x * 256 + threadIdx.x;
  int stride = gridDim.x * 256;
  for (; i < n4; i += stride) {
    float4 v = ((const float4*)x)[i];
    ushort4 h, l;
    h.x = f2bf(v.x); l.x = f2bf(v.x - bf2f(h.x));
    h.y = f2bf(v.y); l.y = f2bf(v.y - bf2f(h.y));
    h.z = f2bf(v.z); l.z = f2bf(v.z - bf2f(h.z));
    h.w = f2bf(v.w); l.w = f2bf(v.w - bf2f(h.w));
    ((ushort4*)xh)[i] = h;
    ((ushort4*)xl)[i] = l;
  }
}

// ---------------- weight prep: W[K][N] f32 -> W^T hi/lo [Npad][K] bf16 ------
__global__ __launch_bounds__(256) void prep_w(const float* __restrict__ W, int N, int K,
                                              int Npad, unsigned short* __restrict__ th,
                                              unsigned short* __restrict__ tl) {
  int i = blockIdx.x * 256 + threadIdx.x;
  if (i >= Npad * K) return;
  int n = i / K, k = i - n * K;
  float v = (n < N) ? W[(size_t)k * N + n] : 0.f;
  unsigned short h = f2bf(v);
  th[i] = h;
  tl[i] = f2bf(v - bf2f(h));
}

// ---------------- MFMA GEMM: C = A @ B, split-bf16, LDS-staged B ----------
// A as hi/lo bf16 [M][K]; B^T as hi/lo bf16 [Npad][K]; Npad = NT*16.
// Block = 4 waves = 128 rows; wave = 32 rows (2 fragments) x NT*16 cols.
// omode: 0 = f32 std (ldc floats); 1 = packed-bf16 head-interleave, uint
// stride ldu = ldc>>1 (uint at (row, d): lo=head0 col d, hi=head1 col d+64;
// NT==8); 2 = bf16 std (ldc ushorts).
template <int K, int NT>
__global__ __launch_bounds__(256) void gemm_mfma(
    const unsigned short* __restrict__ Ah, const unsigned short* __restrict__ Al,
    const unsigned short* __restrict__ BTh0, const unsigned short* __restrict__ BTl0,
    const unsigned short* __restrict__ BTh1, const unsigned short* __restrict__ BTl1,
    void* __restrict__ C0, void* __restrict__ C1,
    int ldc, int M, int Ncols, int omode0, int omode1) {
  constexpr int K2 = K * 2;    // bytes per B^T row
  constexpr int NKT = K / 32;  // k-tiles
  __shared__ unsigned short Bs[2][2][NT * 512];  // [buf][hi/lo][nt*512 + kg*128 + lrow*8]

  const unsigned short* BTh = blockIdx.y ? BTh1 : BTh0;
  const unsigned short* BTl = blockIdx.y ? BTl1 : BTl0;
  void* Cv = blockIdx.y ? C1 : C0;
  const int omode = blockIdx.y ? omode1 : omode0;

  const int wid = threadIdx.x >> 6;
  const int lane = threadIdx.x & 63;
  const int lrow = lane & 15;
  const int kg = lane >> 4;
  const int row0 = blockIdx.x * 128 + wid * 32;
  const int ra = min(row0 + lrow, M - 1);
  const int rb = min(row0 + 16 + lrow, M - 1);
  const size_t aoffA = (size_t)ra * K + kg * 8;
  const size_t aoffB = (size_t)rb * K + kg * 8;

  auto stage = [&](int buf, int kt) {
    for (int j = wid; j < 2 * NT; j += 4) {
      const int h = (j >= NT) ? 1 : 0;
      const int nt = h ? j - NT : j;
      const unsigned short* src = h ? BTl : BTh;
      const char* g = (const char*)src + (size_t)(nt * 16 + lrow) * K2 + kt * 64 + kg * 16;
      unsigned short* l = &Bs[buf][h][nt * 512];
      __builtin_amdgcn_global_load_lds(
          (const __attribute__((address_space(1))) unsigned*)g,
          (__attribute__((address_space(3))) unsigned*)l, 16, 0, 0);
    }
  };

  f32x4 accA[NT] = {};
  f32x4 accB[NT] = {};

  stage(0, 0);
  bf16x8 cahA = *(const bf16x8*)(Ah + aoffA);
  bf16x8 calA = *(const bf16x8*)(Al + aoffA);
  bf16x8 cahB = *(const bf16x8*)(Ah + aoffB);
  bf16x8 calB = *(const bf16x8*)(Al + aoffB);

  for (int kt = 0; kt < NKT; ++kt) {
    __syncthreads();  // buf[kt&1] staged
    if (kt + 1 < NKT) stage((kt + 1) & 1, kt + 1);
    const int kn = (kt + 1 < NKT) ? (kt + 1) * 32 : kt * 32;
    bf16x8 nahA = *(const bf16x8*)(Ah + aoffA + kn);
    bf16x8 nalA = *(const bf16x8*)(Al + aoffA + kn);
    bf16x8 nahB = *(const bf16x8*)(Ah + aoffB + kn);
    bf16x8 nalB = *(const bf16x8*)(Al + aoffB + kn);
    const int buf = kt & 1;
#pragma unroll
    for (int nt = 0; nt < NT; ++nt) {
      bf16x8 bh = ((const bf16x8*)&Bs[buf][0][nt * 512])[lane];
      bf16x8 bl = ((const bf16x8*)&Bs[buf][1][nt * 512])[lane];
      accA[nt] = __builtin_amdgcn_mfma_f32_16x16x32_bf16(cahA, bh, accA[nt], 0, 0, 0);
      accA[nt] = __builtin_amdgcn_mfma_f32_16x16x32_bf16(cahA, bl, accA[nt], 0, 0, 0);
      accA[nt] = __builtin_amdgcn_mfma_f32_16x16x32_bf16(calA, bh, accA[nt], 0, 0, 0);
      accB[nt] = __builtin_amdgcn_mfma_f32_16x16x32_bf16(cahB, bh, accB[nt], 0, 0, 0);
      accB[nt] = __builtin_amdgcn_mfma_f32_16x16x32_bf16(cahB, bl, accB[nt], 0, 0, 0);
      accB[nt] = __builtin_amdgcn_mfma_f32_16x16x32_bf16(calB, bh, accB[nt], 0, 0, 0);
    }
    cahA = nahA; calA = nalA; cahB = nahB; calB = nalB;
  }

  if (omode == 1) {
    // packed-bf16 head-interleave: uint stride = ldc/2
    unsigned* Cu = (unsigned*)Cv;
    const int ldu = ldc >> 1;
#pragma unroll
    for (int nt = 0; nt < NT / 2; ++nt) {
      int d = nt * 16 + lrow;
#pragma unroll
      for (int r = 0; r < 4; ++r) {
        int g0 = row0 + kg * 4 + r;
        if (g0 < M) {
          unsigned p = (unsigned)f2bf(accA[nt][r]) |
                       ((unsigned)f2bf(accA[nt + NT / 2][r]) << 16);
          Cu[(size_t)g0 * ldu + d] = p;
        }
        int g1 = row0 + 16 + kg * 4 + r;
        if (g1 < M) {
          unsigned p = (unsigned)f2bf(accB[nt][r]) |
                       ((unsigned)f2bf(accB[nt + NT / 2][r]) << 16);
          Cu[(size_t)g1 * ldu + d] = p;
        }
      }
    }
  } else if (omode == 2) {
    unsigned short* Cs = (unsigned short*)Cv;
#pragma unroll
    for (int nt = 0; nt < NT; ++nt) {
      int gc = nt * 16 + lrow;
      if (gc >= Ncols) continue;
#pragma unroll
      for (int r = 0; r < 4; ++r) {
        int g0 = row0 + kg * 4 + r;
        if (g0 < M) Cs[(size_t)g0 * ldc + gc] = f2bf(accA[nt][r]);
        int g1 = row0 + 16 + kg * 4 + r;
        if (g1 < M) Cs[(size_t)g1 * ldc + gc] = f2bf(accB[nt][r]);
      }
    }
  } else {
    float* C = (float*)Cv;
#pragma unroll
    for (int nt = 0; nt < NT; ++nt) {
      int gc = nt * 16 + lrow;
      if (gc >= Ncols) continue;
#pragma unroll
      for (int r = 0; r < 4; ++r) {
        int g0 = row0 + kg * 4 + r;
        if (g0 < M) C[(size_t)g0 * ldc + gc] = accA[nt][r];
        int g1 = row0 + 16 + kg * 4 + r;
        if (g1 < M) C[(size_t)g1 * ldc + gc] = accB[nt][r];
      }
    }
  }
}

// ---------------- SAGE aggregation (wave per node) -> h0 bf16 hi/lo --------
// yI: packed 2xbf16 per (node, d) uint, 64 uints/node, table 12.8MB
__global__ __launch_bounds__(256) void sage_agg(const float* __restrict__ z,
                                                const unsigned* __restrict__ yI,
                                                const int* __restrict__ row_start,
                                                const int* __restrict__ csr_src,
                                                const float* __restrict__ b,
                                                unsigned short* __restrict__ h0h,
                                                unsigned short* __restrict__ h0l, int N) {
  int wid = threadIdx.x >> 6;
  int lane = threadIdx.x & 63;
  int n = blockIdx.x * 4 + wid;
  if (n >= N) return;
  int s = row_start[n], e = row_start[n + 1];
  float a0 = 0.f, a1 = 0.f;
  int i = s;
  for (; i + 1 < e; i += 2) {
    unsigned v0 = yI[(size_t)csr_src[i] * 64 + lane];
    unsigned v1 = yI[(size_t)csr_src[i + 1] * 64 + lane];
    float2 f0 = unpk(v0), f1 = unpk(v1);
    a0 += f0.x + f1.x;
    a1 += f0.y + f1.y;
  }
  if (i < e) {
    float2 f = unpk(yI[(size_t)csr_src[i] * 64 + lane]);
    a0 += f.x;
    a1 += f.y;
  }
  float inv = 1.0f / fmaxf((float)(e - s), 1.0f);
  size_t base = (size_t)n * 128;
  float v0 = elu_f(z[base + lane] + a0 * inv + b[lane]);
  float v1 = elu_f(z[base + 64 + lane] + a1 * inv + b[64 + lane]);
  unsigned short hh0 = f2bf(v0), hh1 = f2bf(v1);
  h0h[base + lane] = hh0;
  h0l[base + lane] = f2bf(v0 - bf2f(hh0));
  h0h[base + 64 + lane] = hh1;
  h0l[base + 64 + lane] = f2bf(v1 - bf2f(hh1));
}

// ---------------- per-node attention logits (layer 1) ----------------------
__global__ __launch_bounds__(256) void elr1_kernel(const unsigned* __restrict__ featI,
                                                   const float* __restrict__ al,
                                                   const float* __restrict__ ar,
                                                   float2* __restrict__ el,
                                                   float2* __restrict__ er, int N) {
  int wid = threadIdx.x >> 6;
  int lane = threadIdx.x & 63;
  int n = blockIdx.x * 4 + wid;
  if (n >= N) return;
  float2 f = unpk(featI[(size_t)n * 64 + lane]);
  float e0 = wave_sum(f.x * al[lane]);
  float e1 = wave_sum(f.y * al[64 + lane]);
  float r0 = wave_sum(f.x * ar[lane]);
  float r1 = wave_sum(f.y * ar[64 + lane]);
  if (lane == 0) {
    el[n] = make_float2(e0, e1);
    er[n] = make_float2(r0, r1);
  }
}

// ---------------- attn1: thread per node, softmax weights ------------------
__global__ __launch_bounds__(256) void attn1_kernel(const float2* __restrict__ el,
                                                    const float2* __restrict__ er,
                                                    const int* __restrict__ row_start,
                                                    const int* __restrict__ csr_src,
                                                    float2* __restrict__ alpha,
                                                    float2* __restrict__ inv_s, int N) {
  int n = blockIdx.x * 256 + threadIdx.x;
  if (n >= N) return;
  int beg = row_start[n], end = row_start[n + 1];
  float2 r = er[n];
  float m0 = -INFINITY, m1 = -INFINITY;
  for (int i = beg; i < end; ++i) {
    float2 l = el[csr_src[i]];
    float e0 = l.x + r.x;
    e0 = e0 > 0.f ? e0 : 0.2f * e0;
    float e1 = l.y + r.y;
    e1 = e1 > 0.f ? e1 : 0.2f * e1;
    alpha[i] = make_float2(e0, e1);
    m0 = fmaxf(m0, e0);
    m1 = fmaxf(m1, e1);
  }
  float s0 = 0.f, s1 = 0.f;
  for (int i = beg; i < end; ++i) {
    float2 a = alpha[i];
    float p0 = __expf(a.x - m0);
    float p1 = __expf(a.y - m1);
    s0 += p0;
    s1 += p1;
    alpha[i] = make_float2(p0, p1);
  }
  inv_s[n] = make_float2(1.0f / fmaxf(s0, 1e-9f), 1.0f / fmaxf(s1, 1e-9f));
}

// ---------------- fused GAT layer 1 aggregation -> h1 bf16 hi/lo -----------
__global__ __launch_bounds__(256) void gat1_agg(const unsigned* __restrict__ featI,
                                                const float2* __restrict__ alpha,
                                                const float2* __restrict__ inv_s,
                                                const int* __restrict__ row_start,
                                                const int* __restrict__ csr_src,
                                                const float* __restrict__ b,
                                                unsigned short* __restrict__ h1h,
                                                unsigned short* __restrict__ h1l, int N) {
  int wid = threadIdx.x >> 6;
  int lane = threadIdx.x & 63;
  int n = blockIdx.x * 4 + wid;
  if (n >= N) return;
  int beg = row_start[n], end = row_start[n + 1];
  float a0 = 0.f, a1 = 0.f;
  int i = beg;
  for (; i + 1 < end; i += 2) {
    unsigned v0 = featI[(size_t)csr_src[i] * 64 + lane];
    unsigned v1 = featI[(size_t)csr_src[i + 1] * 64 + lane];
    float2 p0 = alpha[i], p1 = alpha[i + 1];
    float2 f0 = unpk(v0), f1 = unpk(v1);
    a0 = fmaf(p0.x, f0.x, a0);
    a1 = fmaf(p0.y, f0.y, a1);
    a0 = fmaf(p1.x, f1.x, a0);
    a1 = fmaf(p1.y, f1.y, a1);
  }
  if (i < end) {
    float2 p = alpha[i];
    float2 f = unpk(featI[(size_t)csr_src[i] * 64 + lane]);
    a0 = fmaf(p.x, f.x, a0);
    a1 = fmaf(p.y, f.y, a1);
  }
  float2 is = inv_s[n];
  float o0 = elu_f(a0 * is.x + b[lane]);
  float o1 = elu_f(a1 * is.y + b[64 + lane]);
  size_t base = (size_t)n * 128;
  unsigned short hh0 = f2bf(o0), hh1 = f2bf(o1);
  h1h[base + lane] = hh0;
  h1l[base + lane] = f2bf(o0 - bf2f(hh0));
  h1h[base + 64 + lane] = hh1;
  h1l[base + 64 + lane] = f2bf(o1 - bf2f(hh1));
}

// ---------------- per-node attention logits (layer 2) ----------------------
__global__ __launch_bounds__(256) void elr2_kernel(const unsigned short* __restrict__ feat,  // bf16 ld48
                                                   const float* __restrict__ al,
                                                   const float* __restrict__ ar,
                                                   float* __restrict__ el,
                                                   float* __restrict__ er, int N) {
  int wid = threadIdx.x >> 6;
  int lane = threadIdx.x & 63;
  int n = blockIdx.x * 4 + wid;
  if (n >= N) return;
  float f = 0.f, a = 0.f, r = 0.f;
  if (lane < 47) {
    f = bf2f(feat[(size_t)n * 48 + lane]);
    a = al[lane];
    r = ar[lane];
  }
  float e = wave_sum(f * a);
  float rr = wave_sum(f * r);
  if (lane == 0) {
    el[n] = e;
    er[n] = rr;
  }
}

// ---------------- attn2: thread per node ----------------------------------
__global__ __launch_bounds__(256) void attn2_kernel(const float* __restrict__ el,
                                                    const float* __restrict__ er,
                                                    const int* __restrict__ row_start,
                                                    const int* __restrict__ csr_src,
                                                    float* __restrict__ alpha,
                                                    float* __restrict__ inv_s, int N) {
  int n = blockIdx.x * 256 + threadIdx.x;
  if (n >= N) return;
  int beg = row_start[n], end = row_start[n + 1];
  float r = er[n];
  float m = -INFINITY;
  for (int i = beg; i < end; ++i) {
    float e = el[csr_src[i]] + r;
    e = e > 0.f ? e : 0.2f * e;
    alpha[i] = e;
    m = fmaxf(m, e);
  }
  float s = 0.f;
  for (int i = beg; i < end; ++i) {
    float p = __expf(alpha[i] - m);
    s += p;
    alpha[i] = p;
  }
  inv_s[n] = 1.0f / fmaxf(s, 1e-9f);
}

// ---------------- fused GAT layer 2 aggregation -> d_out ------------------
__global__ __launch_bounds__(256) void gat2_agg(const unsigned short* __restrict__ feat,  // bf16 ld48
                                                const float* __restrict__ alpha,
                                                const float* __restrict__ inv_s,
                                                const int* __restrict__ row_start,
                                                const int* __restrict__ csr_src,
                                                const float* __restrict__ b,
                                                float* __restrict__ out, int N) {
  int wid = threadIdx.x >> 6;
  int lane = threadIdx.x & 63;
  int n = blockIdx.x * 4 + wid;
  if (n >= N) return;
  int beg = row_start[n], end = row_start[n + 1];
  int lidx = lane < 47 ? lane : 0;
  float acc = 0.f;
  int i = beg;
  for (; i + 1 < end; i += 2) {
    int u0 = csr_src[i], u1 = csr_src[i + 1];
    float p0 = alpha[i], p1 = alpha[i + 1];
    acc = fmaf(p0, bf2f(feat[(size_t)u0 * 48 + lidx]), acc);
    acc = fmaf(p1, bf2f(feat[(size_t)u1 * 48 + lidx]), acc);
  }
  if (i < end) {
    acc = fmaf(alpha[i], bf2f(feat[(size_t)csr_src[i] * 48 + lidx]), acc);
  }
  if (lane < 47) {
    out[(size_t)n * 47 + lane] = acc * inv_s[n] + b[lane];
  }
}

// ---------------------------------------------------------------------------
extern "C" void kernel_launch(void* const* d_in, const int* in_sizes, int n_in,
                              void* d_out, int out_size, void* d_ws, size_t ws_size,
                              hipStream_t stream) {
  const float* x = (const float*)d_in[0];
  const int* src = (const int*)d_in[1];
  const int* dst = (const int*)d_in[2];
  const float* sage_w_self = (const float*)d_in[3];
  const float* sage_w_neigh = (const float*)d_in[4];
  const float* sage_b = (const float*)d_in[5];
  const float* gat1_w = (const float*)d_in[6];
  const float* gat1_al = (const float*)d_in[7];
  const float* gat1_ar = (const float*)d_in[8];
  const float* gat1_b = (const float*)d_in[9];
  const float* gat2_w = (const float*)d_in[10];
  const float* gat2_al = (const float*)d_in[11];
  const float* gat2_ar = (const float*)d_in[12];
  const float* gat2_b = (const float*)d_in[13];
  float* out = (float*)d_out;

  const int N = in_sizes[0] / 256;
  const int E = in_sizes[1];

  char* ws = (char*)d_ws;
  size_t off = 0;
  auto alloc = [&](size_t bytes) {
    size_t o = off;
    off += (bytes + 255) & ~(size_t)255;
    return o;
  };
  int* deg_i = (int*)(ws + alloc((size_t)N * 4));
  int* row_start = (int*)(ws + alloc((size_t)(N + 1) * 4));
  int* cursor = (int*)(ws + alloc((size_t)N * 4));
  int* csr_src = (int*)(ws + alloc((size_t)E * 4));
  float* bufA = (float*)(ws + alloc((size_t)N * 128 * 4));       // z; later alpha1/alpha2
  unsigned* bufG = (unsigned*)(ws + alloc((size_t)N * 64 * 4));  // yI -> feat1I -> feat2b
  unsigned short* bufX = (unsigned short*)(ws + alloc((size_t)N * 256 * 2 * 2));  // xh|xl
  unsigned short* wt_sh = (unsigned short*)(ws + alloc(128 * 256 * 2));
  unsigned short* wt_sl = (unsigned short*)(ws + alloc(128 * 256 * 2));
  unsigned short* wt_nh = (unsigned short*)(ws + alloc(128 * 256 * 2));
  unsigned short* wt_nl = (unsigned short*)(ws + alloc(128 * 256 * 2));
  unsigned short* wt_1h = (unsigned short*)(ws + alloc(128 * 128 * 2));
  unsigned short* wt_1l = (unsigned short*)(ws + alloc(128 * 128 * 2));
  unsigned short* wt_2h = (unsigned short*)(ws + alloc(48 * 128 * 2));
  unsigned short* wt_2l = (unsigned short*)(ws + alloc(48 * 128 * 2));
  float2* el1 = (float2*)(ws + alloc((size_t)N * 8));
  float2* er1 = (float2*)(ws + alloc((size_t)N * 8));
  float* el2 = (float*)(ws + alloc((size_t)N * 4));
  float* er2 = (float*)(ws + alloc((size_t)N * 4));
  float2* inv_s1 = (float2*)(ws + alloc((size_t)N * 8));
  float* inv_s2 = (float*)(ws + alloc((size_t)N * 4));
  (void)ws_size;
  (void)n_in;
  (void)out_size;

  // lifetimes:
  unsigned short* xh = (unsigned short*)bufX;       // dead after L0 gemm
  unsigned short* xl = bufX + (size_t)N * 256;      // dead after L0 gemm
  float* z = bufA;                                  // dead after sage_agg
  unsigned* yI = bufG;                              // dead after sage_agg
  unsigned short* h0h = bufX;                       // reuse xh region
  unsigned short* h0l = bufX + (size_t)N * 128;
  unsigned* feat1I = bufG;                          // reuse yI; dead after gat1_agg
  float2* alpha1 = (float2*)bufA;                   // reuse z; dead after gat1_agg
  unsigned short* h1h = bufX + (size_t)N * 256;     // reuse xl region
  unsigned short* h1l = bufX + (size_t)N * 256 + (size_t)N * 128;
  unsigned short* feat2b = (unsigned short*)bufG;   // reuse feat1I
  float* alpha2 = bufA;                             // reuse alpha1

  hipMemsetAsync(deg_i, 0, (size_t)N * 4, stream);
  hipMemsetAsync(cursor, 0, (size_t)N * 4, stream);

  const int eb = (E + 255) / 256;
  const int nb4 = (N + 3) / 4;
  const int nb256 = (N + 255) / 256;
  const int gx = (N + 127) / 128;

  split_x<<<2048, 256, 0, stream>>>(x, xh, xl, N * 64);
  prep_w<<<(128 * 256 + 255) / 256, 256, 0, stream>>>(sage_w_self, 128, 256, 128, wt_sh, wt_sl);
  prep_w<<<(128 * 256 + 255) / 256, 256, 0, stream>>>(sage_w_neigh, 128, 256, 128, wt_nh, wt_nl);
  prep_w<<<(128 * 128 + 255) / 256, 256, 0, stream>>>(gat1_w, 128, 128, 128, wt_1h, wt_1l);
  prep_w<<<(48 * 128 + 255) / 256, 256, 0, stream>>>(gat2_w, 47, 128, 48, wt_2h, wt_2l);

  deg_kernel<<<eb, 256, 0, stream>>>(dst, deg_i, E);
  scan_kernel<<<1, 1024, 0, stream>>>(deg_i, row_start, N);
  scatter_kernel<<<eb, 256, 0, stream>>>(src, dst, row_start, cursor, csr_src, E);

  // layer 0: y=0 -> z = x@W_self (f32, ldc=128 floats),
  //          y=1 -> yI = x@W_neigh (packed bf16 ilv, ldu=64 uints)
  {
    dim3 grid(gx, 2);
    gemm_mfma<256, 8><<<grid, 256, 0, stream>>>(xh, xl, wt_sh, wt_sl, wt_nh, wt_nl,
                                                z, yI, 128, N, 128, 0, 1);
  }
  sage_agg<<<nb4, 256, 0, stream>>>(z, yI, row_start, csr_src, sage_b, h0h, h0l, N);

  // GAT layer 1: feat1I = h0 @ gat1_w (packed bf16 ilv, ldc=128 -> ldu=64 uints)
  {
    dim3 grid(gx, 1);
    gemm_mfma<128, 8><<<grid, 256, 0, stream>>>(h0h, h0l, wt_1h, wt_1l, wt_1h, wt_1l,
                                                feat1I, feat1I, 128, N, 128, 1, 1);
  }
  elr1_kernel<<<nb4, 256, 0, stream>>>(feat1I, gat1_al, gat1_ar, el1, er1, N);
  attn1_kernel<<<nb256, 256, 0, stream>>>(el1, er1, row_start, csr_src, alpha1, inv_s1, N);
  gat1_agg<<<nb4, 256, 0, stream>>>(feat1I, alpha1, inv_s1, row_start, csr_src, gat1_b,
                                    h1h, h1l, N);

  // GAT layer 2: feat2b = h1 @ gat2_w (bf16 std, ldc=48 ushorts)
  {
    dim3 grid(gx, 1);
    gemm_mfma<128, 3><<<grid, 256, 0, stream>>>(h1h, h1l, wt_2h, wt_2l, wt_2h, wt_2l,
                                                feat2b, feat2b, 48, N, 47, 2, 2);
  }
  elr2_kernel<<<nb4, 256, 0, stream>>>(feat2b, gat2_al, gat2_ar, el2, er2, N);
  attn2_kernel<<<nb256, 256, 0, stream>>>(el2, er2, row_start, csr_src, alpha2, inv_s2, N);
  gat2_agg<<<nb4, 256, 0, stream>>>(feat2b, alpha2, inv_s2, row_start, csr_src, gat2_b, out, N);
}

// Round 10
// 408.915 us; speedup vs baseline: 1.9783x; 1.0868x over previous
//
#include <hip/hip_runtime.h>

// ---------------------------------------------------------------------------
// GAT_4733053960619: SAGEConv(mean) -> ELU -> GAT(2 heads,64) -> ELU -> GAT(1,47)
// N=50000, E=800000, IN_FEATS=256. All fp32.
//
// R9 = R8 + 4-wide manual unroll (batched loads) in the gather kernels.
// R8's gat1_agg was latency-bound (57us, VALU 30%, HBM-path 24%, occ 66%):
// only 2 outstanding 256B gathers per wave. Now 4 independent gathers issue
// back-to-back per iteration. Accumulation order preserved (bit-identical).
// ---------------------------------------------------------------------------

typedef __attribute__((ext_vector_type(8))) short bf16x8;
typedef __attribute__((ext_vector_type(4))) float f32x4;

__device__ __forceinline__ float wave_sum(float v) {
#pragma unroll
  for (int o = 32; o > 0; o >>= 1) v += __shfl_xor(v, o, 64);
  return v;
}

__device__ __forceinline__ float elu_f(float v) {
  return v > 0.f ? v : __expf(v) - 1.0f;
}

__device__ __forceinline__ unsigned short f2bf(float x) {
  union { float f; unsigned u; } v;
  v.f = x;
  unsigned r = v.u + 0x7FFFu + ((v.u >> 16) & 1u);
  return (unsigned short)(r >> 16);
}

__device__ __forceinline__ float bf2f(unsigned short h) {
  union { unsigned u; float f; } v;
  v.u = ((unsigned)h) << 16;
  return v.f;
}

// packed 2xbf16 (lo=head0, hi=head1) -> (f0, f1)
__device__ __forceinline__ float2 unpk(unsigned v) {
  union { unsigned u; float f; } a, b;
  a.u = v << 16;
  b.u = v & 0xFFFF0000u;
  return make_float2(a.f, b.f);
}

// ---------------- CSR build ----------------
__global__ __launch_bounds__(256) void deg_kernel(const int* __restrict__ dst,
                                                  int* __restrict__ deg, int E) {
  int i = blockIdx.x * 256 + threadIdx.x;
  if (i < E) atomicAdd(&deg[dst[i]], 1);
}

__global__ __launch_bounds__(1024) void scan_kernel(const int* __restrict__ deg,
                                                    int* __restrict__ row_start, int n) {
  __shared__ int wsum[16];
  __shared__ int wpre[16];
  __shared__ int s_carry;
  const int t = threadIdx.x;
  const int lane = t & 63;
  const int w = t >> 6;
  if (t == 0) s_carry = 0;
  __syncthreads();
  for (int base = 0; base < n; base += 1024) {
    int v = (base + t < n) ? deg[base + t] : 0;
    int inc = v;
#pragma unroll
    for (int o = 1; o < 64; o <<= 1) {
      int u = __shfl_up(inc, o, 64);
      if (lane >= o) inc += u;
    }
    if (lane == 63) wsum[w] = inc;
    __syncthreads();
    if (w == 0 && lane < 16) {
      int s = wsum[lane];
      int p = s;
#pragma unroll
      for (int o = 1; o < 16; o <<= 1) {
        int u = __shfl_up(p, o, 64);
        if (lane >= o) p += u;
      }
      wpre[lane] = p - s;
    }
    __syncthreads();
    int carry = s_carry;
    if (base + t < n) row_start[base + t] = carry + wpre[w] + inc - v;
    __syncthreads();
    if (t == 1023) s_carry = carry + wpre[15] + inc;
    __syncthreads();
  }
  if (t == 0) row_start[n] = s_carry;
}

__global__ __launch_bounds__(256) void scatter_kernel(const int* __restrict__ src,
                                                      const int* __restrict__ dst,
                                                      const int* __restrict__ row_start,
                                                      int* __restrict__ cursor,
                                                      int* __restrict__ csr_src, int E) {
  int i = blockIdx.x * 256 + threadIdx.x;
  if (i < E) {
    int d = dst[i];
    int p = atomicAdd(&cursor[d], 1);
    csr_src[row_start[d] + p] = src[i];
  }
}

// ---------------- fp32 -> bf16 hi/lo split (x input) ----------------
__global__ __launch_bounds__(256) void split_x(const float* __restrict__ x,
                                               unsigned short* __restrict__ xh,
                                               unsigned short* __restrict__ xl, int n4) {
  int i = blockIdx.x * 256 + threadIdx.x;
  int stride = gridDim.x * 256;
  for (; i < n4; i += stride) {
    float4 v = ((const float4*)x)[i];
    ushort4 h, l;
    h.x = f2bf(v.x); l.x = f2bf(v.x - bf2f(h.x));
    h.y = f2bf(v.y); l.y = f2bf(v.y - bf2f(h.y));
    h.z = f2bf(v.z); l.z = f2bf(v.z - bf2f(h.z));
    h.w = f2bf(v.w); l.w = f2bf(v.w - bf2f(h.w));
    ((ushort4*)xh)[i] = h;
    ((ushort4*)xl)[i] = l;
  }
}

// ---------------- weight prep: W[K][N] f32 -> W^T hi/lo [Npad][K] bf16 ------
__global__ __launch_bounds__(256) void prep_w(const float* __restrict__ W, int N, int K,
                                              int Npad, unsigned short* __restrict__ th,
                                              unsigned short* __restrict__ tl) {
  int i = blockIdx.x * 256 + threadIdx.x;
  if (i >= Npad * K) return;
  int n = i / K, k = i - n * K;
  float v = (n < N) ? W[(size_t)k * N + n] : 0.f;
  unsigned short h = f2bf(v);
  th[i] = h;
  tl[i] = f2bf(v - bf2f(h));
}

// ---------------- MFMA GEMM: C = A @ B, split-bf16, LDS-staged B ----------
// A as hi/lo bf16 [M][K]; B^T as hi/lo bf16 [Npad][K]; Npad = NT*16.
// Block = 4 waves = 128 rows; wave = 32 rows (2 fragments) x NT*16 cols.
// omode: 0 = f32 std (ldc floats); 1 = packed-bf16 head-interleave, uint
// stride ldu = ldc>>1; 2 = bf16 std (ldc ushorts).
template <int K, int NT>
__global__ __launch_bounds__(256) void gemm_mfma(
    const unsigned short* __restrict__ Ah, const unsigned short* __restrict__ Al,
    const unsigned short* __restrict__ BTh0, const unsigned short* __restrict__ BTl0,
    const unsigned short* __restrict__ BTh1, const unsigned short* __restrict__ BTl1,
    void* __restrict__ C0, void* __restrict__ C1,
    int ldc, int M, int Ncols, int omode0, int omode1) {
  constexpr int K2 = K * 2;    // bytes per B^T row
  constexpr int NKT = K / 32;  // k-tiles
  __shared__ unsigned short Bs[2][2][NT * 512];  // [buf][hi/lo][nt*512 + kg*128 + lrow*8]

  const unsigned short* BTh = blockIdx.y ? BTh1 : BTh0;
  const unsigned short* BTl = blockIdx.y ? BTl1 : BTl0;
  void* Cv = blockIdx.y ? C1 : C0;
  const int omode = blockIdx.y ? omode1 : omode0;

  const int wid = threadIdx.x >> 6;
  const int lane = threadIdx.x & 63;
  const int lrow = lane & 15;
  const int kg = lane >> 4;
  const int row0 = blockIdx.x * 128 + wid * 32;
  const int ra = min(row0 + lrow, M - 1);
  const int rb = min(row0 + 16 + lrow, M - 1);
  const size_t aoffA = (size_t)ra * K + kg * 8;
  const size_t aoffB = (size_t)rb * K + kg * 8;

  auto stage = [&](int buf, int kt) {
    for (int j = wid; j < 2 * NT; j += 4) {
      const int h = (j >= NT) ? 1 : 0;
      const int nt = h ? j - NT : j;
      const unsigned short* src = h ? BTl : BTh;
      const char* g = (const char*)src + (size_t)(nt * 16 + lrow) * K2 + kt * 64 + kg * 16;
      unsigned short* l = &Bs[buf][h][nt * 512];
      __builtin_amdgcn_global_load_lds(
          (const __attribute__((address_space(1))) unsigned*)g,
          (__attribute__((address_space(3))) unsigned*)l, 16, 0, 0);
    }
  };

  f32x4 accA[NT] = {};
  f32x4 accB[NT] = {};

  stage(0, 0);
  bf16x8 cahA = *(const bf16x8*)(Ah + aoffA);
  bf16x8 calA = *(const bf16x8*)(Al + aoffA);
  bf16x8 cahB = *(const bf16x8*)(Ah + aoffB);
  bf16x8 calB = *(const bf16x8*)(Al + aoffB);

  for (int kt = 0; kt < NKT; ++kt) {
    __syncthreads();  // buf[kt&1] staged
    if (kt + 1 < NKT) stage((kt + 1) & 1, kt + 1);
    const int kn = (kt + 1 < NKT) ? (kt + 1) * 32 : kt * 32;
    bf16x8 nahA = *(const bf16x8*)(Ah + aoffA + kn);
    bf16x8 nalA = *(const bf16x8*)(Al + aoffA + kn);
    bf16x8 nahB = *(const bf16x8*)(Ah + aoffB + kn);
    bf16x8 nalB = *(const bf16x8*)(Al + aoffB + kn);
    const int buf = kt & 1;
#pragma unroll
    for (int nt = 0; nt < NT; ++nt) {
      bf16x8 bh = ((const bf16x8*)&Bs[buf][0][nt * 512])[lane];
      bf16x8 bl = ((const bf16x8*)&Bs[buf][1][nt * 512])[lane];
      accA[nt] = __builtin_amdgcn_mfma_f32_16x16x32_bf16(cahA, bh, accA[nt], 0, 0, 0);
      accA[nt] = __builtin_amdgcn_mfma_f32_16x16x32_bf16(cahA, bl, accA[nt], 0, 0, 0);
      accA[nt] = __builtin_amdgcn_mfma_f32_16x16x32_bf16(calA, bh, accA[nt], 0, 0, 0);
      accB[nt] = __builtin_amdgcn_mfma_f32_16x16x32_bf16(cahB, bh, accB[nt], 0, 0, 0);
      accB[nt] = __builtin_amdgcn_mfma_f32_16x16x32_bf16(cahB, bl, accB[nt], 0, 0, 0);
      accB[nt] = __builtin_amdgcn_mfma_f32_16x16x32_bf16(calB, bh, accB[nt], 0, 0, 0);
    }
    cahA = nahA; calA = nalA; cahB = nahB; calB = nalB;
  }

  if (omode == 1) {
    // packed-bf16 head-interleave: uint stride = ldc/2
    unsigned* Cu = (unsigned*)Cv;
    const int ldu = ldc >> 1;
#pragma unroll
    for (int nt = 0; nt < NT / 2; ++nt) {
      int d = nt * 16 + lrow;
#pragma unroll
      for (int r = 0; r < 4; ++r) {
        int g0 = row0 + kg * 4 + r;
        if (g0 < M) {
          unsigned p = (unsigned)f2bf(accA[nt][r]) |
                       ((unsigned)f2bf(accA[nt + NT / 2][r]) << 16);
          Cu[(size_t)g0 * ldu + d] = p;
        }
        int g1 = row0 + 16 + kg * 4 + r;
        if (g1 < M) {
          unsigned p = (unsigned)f2bf(accB[nt][r]) |
                       ((unsigned)f2bf(accB[nt + NT / 2][r]) << 16);
          Cu[(size_t)g1 * ldu + d] = p;
        }
      }
    }
  } else if (omode == 2) {
    unsigned short* Cs = (unsigned short*)Cv;
#pragma unroll
    for (int nt = 0; nt < NT; ++nt) {
      int gc = nt * 16 + lrow;
      if (gc >= Ncols) continue;
#pragma unroll
      for (int r = 0; r < 4; ++r) {
        int g0 = row0 + kg * 4 + r;
        if (g0 < M) Cs[(size_t)g0 * ldc + gc] = f2bf(accA[nt][r]);
        int g1 = row0 + 16 + kg * 4 + r;
        if (g1 < M) Cs[(size_t)g1 * ldc + gc] = f2bf(accB[nt][r]);
      }
    }
  } else {
    float* C = (float*)Cv;
#pragma unroll
    for (int nt = 0; nt < NT; ++nt) {
      int gc = nt * 16 + lrow;
      if (gc >= Ncols) continue;
#pragma unroll
      for (int r = 0; r < 4; ++r) {
        int g0 = row0 + kg * 4 + r;
        if (g0 < M) C[(size_t)g0 * ldc + gc] = accA[nt][r];
        int g1 = row0 + 16 + kg * 4 + r;
        if (g1 < M) C[(size_t)g1 * ldc + gc] = accB[nt][r];
      }
    }
  }
}

// ---------------- SAGE aggregation (wave per node) -> h0 bf16 hi/lo --------
// yI: packed 2xbf16 per (node, d) uint. 4-wide unrolled gathers (MLP).
__global__ __launch_bounds__(256) void sage_agg(const float* __restrict__ z,
                                                const unsigned* __restrict__ yI,
                                                const int* __restrict__ row_start,
                                                const int* __restrict__ csr_src,
                                                const float* __restrict__ b,
                                                unsigned short* __restrict__ h0h,
                                                unsigned short* __restrict__ h0l, int N) {
  int wid = threadIdx.x >> 6;
  int lane = threadIdx.x & 63;
  int n = blockIdx.x * 4 + wid;
  if (n >= N) return;
  int s = row_start[n], e = row_start[n + 1];
  float a0 = 0.f, a1 = 0.f;
  int i = s;
  for (; i + 3 < e; i += 4) {
    int u0 = csr_src[i], u1 = csr_src[i + 1], u2 = csr_src[i + 2], u3 = csr_src[i + 3];
    unsigned v0 = yI[(size_t)u0 * 64 + lane];
    unsigned v1 = yI[(size_t)u1 * 64 + lane];
    unsigned v2 = yI[(size_t)u2 * 64 + lane];
    unsigned v3 = yI[(size_t)u3 * 64 + lane];
    float2 f0 = unpk(v0), f1 = unpk(v1), f2 = unpk(v2), f3 = unpk(v3);
    a0 += f0.x + f1.x;
    a1 += f0.y + f1.y;
    a0 += f2.x + f3.x;
    a1 += f2.y + f3.y;
  }
  for (; i < e; ++i) {
    float2 f = unpk(yI[(size_t)csr_src[i] * 64 + lane]);
    a0 += f.x;
    a1 += f.y;
  }
  float inv = 1.0f / fmaxf((float)(e - s), 1.0f);
  size_t base = (size_t)n * 128;
  float v0 = elu_f(z[base + lane] + a0 * inv + b[lane]);
  float v1 = elu_f(z[base + 64 + lane] + a1 * inv + b[64 + lane]);
  unsigned short hh0 = f2bf(v0), hh1 = f2bf(v1);
  h0h[base + lane] = hh0;
  h0l[base + lane] = f2bf(v0 - bf2f(hh0));
  h0h[base + 64 + lane] = hh1;
  h0l[base + 64 + lane] = f2bf(v1 - bf2f(hh1));
}

// ---------------- per-node attention logits (layer 1) ----------------------
__global__ __launch_bounds__(256) void elr1_kernel(const unsigned* __restrict__ featI,
                                                   const float* __restrict__ al,
                                                   const float* __restrict__ ar,
                                                   float2* __restrict__ el,
                                                   float2* __restrict__ er, int N) {
  int wid = threadIdx.x >> 6;
  int lane = threadIdx.x & 63;
  int n = blockIdx.x * 4 + wid;
  if (n >= N) return;
  float2 f = unpk(featI[(size_t)n * 64 + lane]);
  float e0 = wave_sum(f.x * al[lane]);
  float e1 = wave_sum(f.y * al[64 + lane]);
  float r0 = wave_sum(f.x * ar[lane]);
  float r1 = wave_sum(f.y * ar[64 + lane]);
  if (lane == 0) {
    el[n] = make_float2(e0, e1);
    er[n] = make_float2(r0, r1);
  }
}

// ---------------- attn1: thread per node, softmax weights ------------------
__global__ __launch_bounds__(256) void attn1_kernel(const float2* __restrict__ el,
                                                    const float2* __restrict__ er,
                                                    const int* __restrict__ row_start,
                                                    const int* __restrict__ csr_src,
                                                    float2* __restrict__ alpha,
                                                    float2* __restrict__ inv_s, int N) {
  int n = blockIdx.x * 256 + threadIdx.x;
  if (n >= N) return;
  int beg = row_start[n], end = row_start[n + 1];
  float2 r = er[n];
  float m0 = -INFINITY, m1 = -INFINITY;
  for (int i = beg; i < end; ++i) {
    float2 l = el[csr_src[i]];
    float e0 = l.x + r.x;
    e0 = e0 > 0.f ? e0 : 0.2f * e0;
    float e1 = l.y + r.y;
    e1 = e1 > 0.f ? e1 : 0.2f * e1;
    alpha[i] = make_float2(e0, e1);
    m0 = fmaxf(m0, e0);
    m1 = fmaxf(m1, e1);
  }
  float s0 = 0.f, s1 = 0.f;
  for (int i = beg; i < end; ++i) {
    float2 a = alpha[i];
    float p0 = __expf(a.x - m0);
    float p1 = __expf(a.y - m1);
    s0 += p0;
    s1 += p1;
    alpha[i] = make_float2(p0, p1);
  }
  inv_s[n] = make_float2(1.0f / fmaxf(s0, 1e-9f), 1.0f / fmaxf(s1, 1e-9f));
}

// ---------------- fused GAT layer 1 aggregation -> h1 bf16 hi/lo -----------
// 4-wide unrolled gathers (MLP).
__global__ __launch_bounds__(256) void gat1_agg(const unsigned* __restrict__ featI,
                                                const float2* __restrict__ alpha,
                                                const float2* __restrict__ inv_s,
                                                const int* __restrict__ row_start,
                                                const int* __restrict__ csr_src,
                                                const float* __restrict__ b,
                                                unsigned short* __restrict__ h1h,
                                                unsigned short* __restrict__ h1l, int N) {
  int wid = threadIdx.x >> 6;
  int lane = threadIdx.x & 63;
  int n = blockIdx.x * 4 + wid;
  if (n >= N) return;
  int beg = row_start[n], end = row_start[n + 1];
  float a0 = 0.f, a1 = 0.f;
  int i = beg;
  for (; i + 3 < end; i += 4) {
    int u0 = csr_src[i], u1 = csr_src[i + 1], u2 = csr_src[i + 2], u3 = csr_src[i + 3];
    unsigned v0 = featI[(size_t)u0 * 64 + lane];
    unsigned v1 = featI[(size_t)u1 * 64 + lane];
    unsigned v2 = featI[(size_t)u2 * 64 + lane];
    unsigned v3 = featI[(size_t)u3 * 64 + lane];
    float2 p0 = alpha[i], p1 = alpha[i + 1], p2 = alpha[i + 2], p3 = alpha[i + 3];
    float2 f0 = unpk(v0), f1 = unpk(v1), f2 = unpk(v2), f3 = unpk(v3);
    a0 = fmaf(p0.x, f0.x, a0);
    a1 = fmaf(p0.y, f0.y, a1);
    a0 = fmaf(p1.x, f1.x, a0);
    a1 = fmaf(p1.y, f1.y, a1);
    a0 = fmaf(p2.x, f2.x, a0);
    a1 = fmaf(p2.y, f2.y, a1);
    a0 = fmaf(p3.x, f3.x, a0);
    a1 = fmaf(p3.y, f3.y, a1);
  }
  for (; i < end; ++i) {
    float2 p = alpha[i];
    float2 f = unpk(featI[(size_t)csr_src[i] * 64 + lane]);
    a0 = fmaf(p.x, f.x, a0);
    a1 = fmaf(p.y, f.y, a1);
  }
  float2 is = inv_s[n];
  float o0 = elu_f(a0 * is.x + b[lane]);
  float o1 = elu_f(a1 * is.y + b[64 + lane]);
  size_t base = (size_t)n * 128;
  unsigned short hh0 = f2bf(o0), hh1 = f2bf(o1);
  h1h[base + lane] = hh0;
  h1l[base + lane] = f2bf(o0 - bf2f(hh0));
  h1h[base + 64 + lane] = hh1;
  h1l[base + 64 + lane] = f2bf(o1 - bf2f(hh1));
}

// ---------------- per-node attention logits (layer 2) ----------------------
__global__ __launch_bounds__(256) void elr2_kernel(const unsigned short* __restrict__ feat,  // bf16 ld48
                                                   const float* __restrict__ al,
                                                   const float* __restrict__ ar,
                                                   float* __restrict__ el,
                                                   float* __restrict__ er, int N) {
  int wid = threadIdx.x >> 6;
  int lane = threadIdx.x & 63;
  int n = blockIdx.x * 4 + wid;
  if (n >= N) return;
  float f = 0.f, a = 0.f, r = 0.f;
  if (lane < 47) {
    f = bf2f(feat[(size_t)n * 48 + lane]);
    a = al[lane];
    r = ar[lane];
  }
  float e = wave_sum(f * a);
  float rr = wave_sum(f * r);
  if (lane == 0) {
    el[n] = e;
    er[n] = rr;
  }
}

// ---------------- attn2: thread per node ----------------------------------
__global__ __launch_bounds__(256) void attn2_kernel(const float* __restrict__ el,
                                                    const float* __restrict__ er,
                                                    const int* __restrict__ row_start,
                                                    const int* __restrict__ csr_src,
                                                    float* __restrict__ alpha,
                                                    float* __restrict__ inv_s, int N) {
  int n = blockIdx.x * 256 + threadIdx.x;
  if (n >= N) return;
  int beg = row_start[n], end = row_start[n + 1];
  float r = er[n];
  float m = -INFINITY;
  for (int i = beg; i < end; ++i) {
    float e = el[csr_src[i]] + r;
    e = e > 0.f ? e : 0.2f * e;
    alpha[i] = e;
    m = fmaxf(m, e);
  }
  float s = 0.f;
  for (int i = beg; i < end; ++i) {
    float p = __expf(alpha[i] - m);
    s += p;
    alpha[i] = p;
  }
  inv_s[n] = 1.0f / fmaxf(s, 1e-9f);
}

// ---------------- fused GAT layer 2 aggregation -> d_out ------------------
// 4-wide unrolled gathers (MLP).
__global__ __launch_bounds__(256) void gat2_agg(const unsigned short* __restrict__ feat,  // bf16 ld48
                                                const float* __restrict__ alpha,
                                                const float* __restrict__ inv_s,
                                                const int* __restrict__ row_start,
                                                const int* __restrict__ csr_src,
                                                const float* __restrict__ b,
                                                float* __restrict__ out, int N) {
  int wid = threadIdx.x >> 6;
  int lane = threadIdx.x & 63;
  int n = blockIdx.x * 4 + wid;
  if (n >= N) return;
  int beg = row_start[n], end = row_start[n + 1];
  int lidx = lane < 47 ? lane : 0;
  float acc = 0.f;
  int i = beg;
  for (; i + 3 < end; i += 4) {
    int u0 = csr_src[i], u1 = csr_src[i + 1], u2 = csr_src[i + 2], u3 = csr_src[i + 3];
    float g0 = bf2f(feat[(size_t)u0 * 48 + lidx]);
    float g1 = bf2f(feat[(size_t)u1 * 48 + lidx]);
    float g2 = bf2f(feat[(size_t)u2 * 48 + lidx]);
    float g3 = bf2f(feat[(size_t)u3 * 48 + lidx]);
    float p0 = alpha[i], p1 = alpha[i + 1], p2 = alpha[i + 2], p3 = alpha[i + 3];
    acc = fmaf(p0, g0, acc);
    acc = fmaf(p1, g1, acc);
    acc = fmaf(p2, g2, acc);
    acc = fmaf(p3, g3, acc);
  }
  for (; i < end; ++i) {
    acc = fmaf(alpha[i], bf2f(feat[(size_t)csr_src[i] * 48 + lidx]), acc);
  }
  if (lane < 47) {
    out[(size_t)n * 47 + lane] = acc * inv_s[n] + b[lane];
  }
}

// ---------------------------------------------------------------------------
extern "C" void kernel_launch(void* const* d_in, const int* in_sizes, int n_in,
                              void* d_out, int out_size, void* d_ws, size_t ws_size,
                              hipStream_t stream) {
  const float* x = (const float*)d_in[0];
  const int* src = (const int*)d_in[1];
  const int* dst = (const int*)d_in[2];
  const float* sage_w_self = (const float*)d_in[3];
  const float* sage_w_neigh = (const float*)d_in[4];
  const float* sage_b = (const float*)d_in[5];
  const float* gat1_w = (const float*)d_in[6];
  const float* gat1_al = (const float*)d_in[7];
  const float* gat1_ar = (const float*)d_in[8];
  const float* gat1_b = (const float*)d_in[9];
  const float* gat2_w = (const float*)d_in[10];
  const float* gat2_al = (const float*)d_in[11];
  const float* gat2_ar = (const float*)d_in[12];
  const float* gat2_b = (const float*)d_in[13];
  float* out = (float*)d_out;

  const int N = in_sizes[0] / 256;
  const int E = in_sizes[1];

  char* ws = (char*)d_ws;
  size_t off = 0;
  auto alloc = [&](size_t bytes) {
    size_t o = off;
    off += (bytes + 255) & ~(size_t)255;
    return o;
  };
  int* deg_i = (int*)(ws + alloc((size_t)N * 4));
  int* row_start = (int*)(ws + alloc((size_t)(N + 1) * 4));
  int* cursor = (int*)(ws + alloc((size_t)N * 4));
  int* csr_src = (int*)(ws + alloc((size_t)E * 4));
  float* bufA = (float*)(ws + alloc((size_t)N * 128 * 4));       // z; later alpha1/alpha2
  unsigned* bufG = (unsigned*)(ws + alloc((size_t)N * 64 * 4));  // yI -> feat1I -> feat2b
  unsigned short* bufX = (unsigned short*)(ws + alloc((size_t)N * 256 * 2 * 2));  // xh|xl
  unsigned short* wt_sh = (unsigned short*)(ws + alloc(128 * 256 * 2));
  unsigned short* wt_sl = (unsigned short*)(ws + alloc(128 * 256 * 2));
  unsigned short* wt_nh = (unsigned short*)(ws + alloc(128 * 256 * 2));
  unsigned short* wt_nl = (unsigned short*)(ws + alloc(128 * 256 * 2));
  unsigned short* wt_1h = (unsigned short*)(ws + alloc(128 * 128 * 2));
  unsigned short* wt_1l = (unsigned short*)(ws + alloc(128 * 128 * 2));
  unsigned short* wt_2h = (unsigned short*)(ws + alloc(48 * 128 * 2));
  unsigned short* wt_2l = (unsigned short*)(ws + alloc(48 * 128 * 2));
  float2* el1 = (float2*)(ws + alloc((size_t)N * 8));
  float2* er1 = (float2*)(ws + alloc((size_t)N * 8));
  float* el2 = (float*)(ws + alloc((size_t)N * 4));
  float* er2 = (float*)(ws + alloc((size_t)N * 4));
  float2* inv_s1 = (float2*)(ws + alloc((size_t)N * 8));
  float* inv_s2 = (float*)(ws + alloc((size_t)N * 4));
  (void)ws_size;
  (void)n_in;
  (void)out_size;

  // lifetimes:
  unsigned short* xh = (unsigned short*)bufX;       // dead after L0 gemm
  unsigned short* xl = bufX + (size_t)N * 256;      // dead after L0 gemm
  float* z = bufA;                                  // dead after sage_agg
  unsigned* yI = bufG;                              // dead after sage_agg
  unsigned short* h0h = bufX;                       // reuse xh region
  unsigned short* h0l = bufX + (size_t)N * 128;
  unsigned* feat1I = bufG;                          // reuse yI; dead after gat1_agg
  float2* alpha1 = (float2*)bufA;                   // reuse z; dead after gat1_agg
  unsigned short* h1h = bufX + (size_t)N * 256;     // reuse xl region
  unsigned short* h1l = bufX + (size_t)N * 256 + (size_t)N * 128;
  unsigned short* feat2b = (unsigned short*)bufG;   // reuse feat1I
  float* alpha2 = bufA;                             // reuse alpha1

  hipMemsetAsync(deg_i, 0, (size_t)N * 4, stream);
  hipMemsetAsync(cursor, 0, (size_t)N * 4, stream);

  const int eb = (E + 255) / 256;
  const int nb4 = (N + 3) / 4;
  const int nb256 = (N + 255) / 256;
  const int gx = (N + 127) / 128;

  split_x<<<2048, 256, 0, stream>>>(x, xh, xl, N * 64);
  prep_w<<<(128 * 256 + 255) / 256, 256, 0, stream>>>(sage_w_self, 128, 256, 128, wt_sh, wt_sl);
  prep_w<<<(128 * 256 + 255) / 256, 256, 0, stream>>>(sage_w_neigh, 128, 256, 128, wt_nh, wt_nl);
  prep_w<<<(128 * 128 + 255) / 256, 256, 0, stream>>>(gat1_w, 128, 128, 128, wt_1h, wt_1l);
  prep_w<<<(48 * 128 + 255) / 256, 256, 0, stream>>>(gat2_w, 47, 128, 48, wt_2h, wt_2l);

  deg_kernel<<<eb, 256, 0, stream>>>(dst, deg_i, E);
  scan_kernel<<<1, 1024, 0, stream>>>(deg_i, row_start, N);
  scatter_kernel<<<eb, 256, 0, stream>>>(src, dst, row_start, cursor, csr_src, E);

  // layer 0: y=0 -> z = x@W_self (f32, ldc=128 floats),
  //          y=1 -> yI = x@W_neigh (packed bf16 ilv, ldu=64 uints)
  {
    dim3 grid(gx, 2);
    gemm_mfma<256, 8><<<grid, 256, 0, stream>>>(xh, xl, wt_sh, wt_sl, wt_nh, wt_nl,
                                                z, yI, 128, N, 128, 0, 1);
  }
  sage_agg<<<nb4, 256, 0, stream>>>(z, yI, row_start, csr_src, sage_b, h0h, h0l, N);

  // GAT layer 1: feat1I = h0 @ gat1_w (packed bf16 ilv, ldc=128 -> ldu=64 uints)
  {
    dim3 grid(gx, 1);
    gemm_mfma<128, 8><<<grid, 256, 0, stream>>>(h0h, h0l, wt_1h, wt_1l, wt_1h, wt_1l,
                                                feat1I, feat1I, 128, N, 128, 1, 1);
  }
  elr1_kernel<<<nb4, 256, 0, stream>>>(feat1I, gat1_al, gat1_ar, el1, er1, N);
  attn1_kernel<<<nb256, 256, 0, stream>>>(el1, er1, row_start, csr_src, alpha1, inv_s1, N);
  gat1_agg<<<nb4, 256, 0, stream>>>(feat1I, alpha1, inv_s1, row_start, csr_src, gat1_b,
                                    h1h, h1l, N);

  // GAT layer 2: feat2b = h1 @ gat2_w (bf16 std, ldc=48 ushorts)
  {
    dim3 grid(gx, 1);
    gemm_mfma<128, 3><<<grid, 256, 0, stream>>>(h1h, h1l, wt_2h, wt_2l, wt_2h, wt_2l,
                                                feat2b, feat2b, 48, N, 47, 2, 2);
  }
  elr2_kernel<<<nb4, 256, 0, stream>>>(feat2b, gat2_al, gat2_ar, el2, er2, N);
  attn2_kernel<<<nb256, 256, 0, stream>>>(el2, er2, row_start, csr_src, alpha2, inv_s2, N);
  gat2_agg<<<nb4, 256, 0, stream>>>(feat2b, alpha2, inv_s2, row_start, csr_src, gat2_b, out, N);
}

// Round 11
// 367.383 us; speedup vs baseline: 2.2020x; 1.1130x over previous
//
#include <hip/hip_runtime.h>

// ---------------------------------------------------------------------------
// GAT_4733053960619: SAGEConv(mean) -> ELU -> GAT(2 heads,64) -> ELU -> GAT(1,47)
// N=50000, E=800000, IN_FEATS=256. All fp32.
//
// R10 = R9 + (a) multi-block scan (the 47us single-block scan_kernel left
// 255 CUs idle; now partial-sums -> wave-scan of partials -> per-chunk final,
// ~10us total) + (b) 8-wide gather unroll in agg kernels (more MLP).
// ---------------------------------------------------------------------------

typedef __attribute__((ext_vector_type(8))) short bf16x8;
typedef __attribute__((ext_vector_type(4))) float f32x4;

__device__ __forceinline__ float wave_sum(float v) {
#pragma unroll
  for (int o = 32; o > 0; o >>= 1) v += __shfl_xor(v, o, 64);
  return v;
}

__device__ __forceinline__ int wave_sum_i(int v) {
#pragma unroll
  for (int o = 32; o > 0; o >>= 1) v += __shfl_xor(v, o, 64);
  return v;
}

__device__ __forceinline__ float elu_f(float v) {
  return v > 0.f ? v : __expf(v) - 1.0f;
}

__device__ __forceinline__ unsigned short f2bf(float x) {
  union { float f; unsigned u; } v;
  v.f = x;
  unsigned r = v.u + 0x7FFFu + ((v.u >> 16) & 1u);
  return (unsigned short)(r >> 16);
}

__device__ __forceinline__ float bf2f(unsigned short h) {
  union { unsigned u; float f; } v;
  v.u = ((unsigned)h) << 16;
  return v.f;
}

// packed 2xbf16 (lo=head0, hi=head1) -> (f0, f1)
__device__ __forceinline__ float2 unpk(unsigned v) {
  union { unsigned u; float f; } a, b;
  a.u = v << 16;
  b.u = v & 0xFFFF0000u;
  return make_float2(a.f, b.f);
}

// ---------------- CSR build ----------------
__global__ __launch_bounds__(256) void deg_kernel(const int* __restrict__ dst,
                                                  int* __restrict__ deg, int E) {
  int i = blockIdx.x * 256 + threadIdx.x;
  if (i < E) atomicAdd(&deg[dst[i]], 1);
}

// phase 1: per-1024-chunk sums
__global__ __launch_bounds__(256) void scan_partial(const int* __restrict__ deg,
                                                    int* __restrict__ psum, int n) {
  __shared__ int red[4];
  const int t = threadIdx.x;
  const int base = blockIdx.x * 1024;
  int s = 0;
#pragma unroll
  for (int j = 0; j < 4; ++j) {
    int idx = base + t + j * 256;
    s += (idx < n) ? deg[idx] : 0;
  }
  s = wave_sum_i(s);
  const int lane = t & 63, w = t >> 6;
  if (lane == 0) red[w] = s;
  __syncthreads();
  if (t == 0) psum[blockIdx.x] = red[0] + red[1] + red[2] + red[3];
}

// phase 2: exclusive scan of partials (single wave, carry loop)
__global__ __launch_bounds__(64) void scan_psum(int* __restrict__ psum, int PB) {
  const int lane = threadIdx.x;
  int carry = 0;
  for (int base = 0; base < PB; base += 64) {
    int v = (base + lane < PB) ? psum[base + lane] : 0;
    int inc = v;
#pragma unroll
    for (int o = 1; o < 64; o <<= 1) {
      int u = __shfl_up(inc, o, 64);
      if (lane >= o) inc += u;
    }
    if (base + lane < PB) psum[base + lane] = carry + inc - v;
    carry += __shfl(inc, 63, 64);
  }
}

// phase 3: per-chunk exclusive scan + block offset -> row_start
__global__ __launch_bounds__(256) void scan_final(const int* __restrict__ deg,
                                                  const int* __restrict__ psum,
                                                  int* __restrict__ row_start,
                                                  int n, int E) {
  __shared__ int woff[4];
  const int t = threadIdx.x;
  const int lane = t & 63, w = t >> 6;
  const int base = blockIdx.x * 1024 + t * 4;
  int d0 = (base + 0 < n) ? deg[base + 0] : 0;
  int d1 = (base + 1 < n) ? deg[base + 1] : 0;
  int d2 = (base + 2 < n) ? deg[base + 2] : 0;
  int d3 = (base + 3 < n) ? deg[base + 3] : 0;
  int l0 = d0, l1 = l0 + d1, l2 = l1 + d2, l3 = l2 + d3;
  int inc = l3;
#pragma unroll
  for (int o = 1; o < 64; o <<= 1) {
    int u = __shfl_up(inc, o, 64);
    if (lane >= o) inc += u;
  }
  int texc = inc - l3;  // exclusive within wave
  if (lane == 63) woff[w] = inc;
  __syncthreads();
  int wo = 0;
  if (w == 0 && lane < 4) {
    int s = woff[lane];
    int p = s;
#pragma unroll
    for (int o = 1; o < 4; o <<= 1) {
      int u = __shfl_up(p, o, 64);
      if (lane >= o) p += u;
    }
    woff[lane] = p - s;  // exclusive wave offsets
  }
  __syncthreads();
  wo = woff[w];
  const int boff = psum[blockIdx.x] + wo + texc;
  if (base + 0 < n) row_start[base + 0] = boff;
  if (base + 1 < n) row_start[base + 1] = boff + l0;
  if (base + 2 < n) row_start[base + 2] = boff + l1;
  if (base + 3 < n) row_start[base + 3] = boff + l2;
  if (blockIdx.x == 0 && t == 0) row_start[n] = E;
}

__global__ __launch_bounds__(256) void scatter_kernel(const int* __restrict__ src,
                                                      const int* __restrict__ dst,
                                                      const int* __restrict__ row_start,
                                                      int* __restrict__ cursor,
                                                      int* __restrict__ csr_src, int E) {
  int i = blockIdx.x * 256 + threadIdx.x;
  if (i < E) {
    int d = dst[i];
    int p = atomicAdd(&cursor[d], 1);
    csr_src[row_start[d] + p] = src[i];
  }
}

// ---------------- fp32 -> bf16 hi/lo split (x input) ----------------
__global__ __launch_bounds__(256) void split_x(const float* __restrict__ x,
                                               unsigned short* __restrict__ xh,
                                               unsigned short* __restrict__ xl, int n4) {
  int i = blockIdx.x * 256 + threadIdx.x;
  int stride = gridDim.x * 256;
  for (; i < n4; i += stride) {
    float4 v = ((const float4*)x)[i];
    ushort4 h, l;
    h.x = f2bf(v.x); l.x = f2bf(v.x - bf2f(h.x));
    h.y = f2bf(v.y); l.y = f2bf(v.y - bf2f(h.y));
    h.z = f2bf(v.z); l.z = f2bf(v.z - bf2f(h.z));
    h.w = f2bf(v.w); l.w = f2bf(v.w - bf2f(h.w));
    ((ushort4*)xh)[i] = h;
    ((ushort4*)xl)[i] = l;
  }
}

// ---------------- weight prep: W[K][N] f32 -> W^T hi/lo [Npad][K] bf16 ------
__global__ __launch_bounds__(256) void prep_w(const float* __restrict__ W, int N, int K,
                                              int Npad, unsigned short* __restrict__ th,
                                              unsigned short* __restrict__ tl) {
  int i = blockIdx.x * 256 + threadIdx.x;
  if (i >= Npad * K) return;
  int n = i / K, k = i - n * K;
  float v = (n < N) ? W[(size_t)k * N + n] : 0.f;
  unsigned short h = f2bf(v);
  th[i] = h;
  tl[i] = f2bf(v - bf2f(h));
}

// ---------------- MFMA GEMM: C = A @ B, split-bf16, LDS-staged B ----------
// A as hi/lo bf16 [M][K]; B^T as hi/lo bf16 [Npad][K]; Npad = NT*16.
// Block = 4 waves = 128 rows; wave = 32 rows (2 fragments) x NT*16 cols.
// omode: 0 = f32 std (ldc floats); 1 = packed-bf16 head-interleave, uint
// stride ldu = ldc>>1; 2 = bf16 std (ldc ushorts).
template <int K, int NT>
__global__ __launch_bounds__(256) void gemm_mfma(
    const unsigned short* __restrict__ Ah, const unsigned short* __restrict__ Al,
    const unsigned short* __restrict__ BTh0, const unsigned short* __restrict__ BTl0,
    const unsigned short* __restrict__ BTh1, const unsigned short* __restrict__ BTl1,
    void* __restrict__ C0, void* __restrict__ C1,
    int ldc, int M, int Ncols, int omode0, int omode1) {
  constexpr int K2 = K * 2;    // bytes per B^T row
  constexpr int NKT = K / 32;  // k-tiles
  __shared__ unsigned short Bs[2][2][NT * 512];  // [buf][hi/lo][nt*512 + kg*128 + lrow*8]

  const unsigned short* BTh = blockIdx.y ? BTh1 : BTh0;
  const unsigned short* BTl = blockIdx.y ? BTl1 : BTl0;
  void* Cv = blockIdx.y ? C1 : C0;
  const int omode = blockIdx.y ? omode1 : omode0;

  const int wid = threadIdx.x >> 6;
  const int lane = threadIdx.x & 63;
  const int lrow = lane & 15;
  const int kg = lane >> 4;
  const int row0 = blockIdx.x * 128 + wid * 32;
  const int ra = min(row0 + lrow, M - 1);
  const int rb = min(row0 + 16 + lrow, M - 1);
  const size_t aoffA = (size_t)ra * K + kg * 8;
  const size_t aoffB = (size_t)rb * K + kg * 8;

  auto stage = [&](int buf, int kt) {
    for (int j = wid; j < 2 * NT; j += 4) {
      const int h = (j >= NT) ? 1 : 0;
      const int nt = h ? j - NT : j;
      const unsigned short* src = h ? BTl : BTh;
      const char* g = (const char*)src + (size_t)(nt * 16 + lrow) * K2 + kt * 64 + kg * 16;
      unsigned short* l = &Bs[buf][h][nt * 512];
      __builtin_amdgcn_global_load_lds(
          (const __attribute__((address_space(1))) unsigned*)g,
          (__attribute__((address_space(3))) unsigned*)l, 16, 0, 0);
    }
  };

  f32x4 accA[NT] = {};
  f32x4 accB[NT] = {};

  stage(0, 0);
  bf16x8 cahA = *(const bf16x8*)(Ah + aoffA);
  bf16x8 calA = *(const bf16x8*)(Al + aoffA);
  bf16x8 cahB = *(const bf16x8*)(Ah + aoffB);
  bf16x8 calB = *(const bf16x8*)(Al + aoffB);

  for (int kt = 0; kt < NKT; ++kt) {
    __syncthreads();  // buf[kt&1] staged
    if (kt + 1 < NKT) stage((kt + 1) & 1, kt + 1);
    const int kn = (kt + 1 < NKT) ? (kt + 1) * 32 : kt * 32;
    bf16x8 nahA = *(const bf16x8*)(Ah + aoffA + kn);
    bf16x8 nalA = *(const bf16x8*)(Al + aoffA + kn);
    bf16x8 nahB = *(const bf16x8*)(Ah + aoffB + kn);
    bf16x8 nalB = *(const bf16x8*)(Al + aoffB + kn);
    const int buf = kt & 1;
#pragma unroll
    for (int nt = 0; nt < NT; ++nt) {
      bf16x8 bh = ((const bf16x8*)&Bs[buf][0][nt * 512])[lane];
      bf16x8 bl = ((const bf16x8*)&Bs[buf][1][nt * 512])[lane];
      accA[nt] = __builtin_amdgcn_mfma_f32_16x16x32_bf16(cahA, bh, accA[nt], 0, 0, 0);
      accA[nt] = __builtin_amdgcn_mfma_f32_16x16x32_bf16(cahA, bl, accA[nt], 0, 0, 0);
      accA[nt] = __builtin_amdgcn_mfma_f32_16x16x32_bf16(calA, bh, accA[nt], 0, 0, 0);
      accB[nt] = __builtin_amdgcn_mfma_f32_16x16x32_bf16(cahB, bh, accB[nt], 0, 0, 0);
      accB[nt] = __builtin_amdgcn_mfma_f32_16x16x32_bf16(cahB, bl, accB[nt], 0, 0, 0);
      accB[nt] = __builtin_amdgcn_mfma_f32_16x16x32_bf16(calB, bh, accB[nt], 0, 0, 0);
    }
    cahA = nahA; calA = nalA; cahB = nahB; calB = nalB;
  }

  if (omode == 1) {
    // packed-bf16 head-interleave: uint stride = ldc/2
    unsigned* Cu = (unsigned*)Cv;
    const int ldu = ldc >> 1;
#pragma unroll
    for (int nt = 0; nt < NT / 2; ++nt) {
      int d = nt * 16 + lrow;
#pragma unroll
      for (int r = 0; r < 4; ++r) {
        int g0 = row0 + kg * 4 + r;
        if (g0 < M) {
          unsigned p = (unsigned)f2bf(accA[nt][r]) |
                       ((unsigned)f2bf(accA[nt + NT / 2][r]) << 16);
          Cu[(size_t)g0 * ldu + d] = p;
        }
        int g1 = row0 + 16 + kg * 4 + r;
        if (g1 < M) {
          unsigned p = (unsigned)f2bf(accB[nt][r]) |
                       ((unsigned)f2bf(accB[nt + NT / 2][r]) << 16);
          Cu[(size_t)g1 * ldu + d] = p;
        }
      }
    }
  } else if (omode == 2) {
    unsigned short* Cs = (unsigned short*)Cv;
#pragma unroll
    for (int nt = 0; nt < NT; ++nt) {
      int gc = nt * 16 + lrow;
      if (gc >= Ncols) continue;
#pragma unroll
      for (int r = 0; r < 4; ++r) {
        int g0 = row0 + kg * 4 + r;
        if (g0 < M) Cs[(size_t)g0 * ldc + gc] = f2bf(accA[nt][r]);
        int g1 = row0 + 16 + kg * 4 + r;
        if (g1 < M) Cs[(size_t)g1 * ldc + gc] = f2bf(accB[nt][r]);
      }
    }
  } else {
    float* C = (float*)Cv;
#pragma unroll
    for (int nt = 0; nt < NT; ++nt) {
      int gc = nt * 16 + lrow;
      if (gc >= Ncols) continue;
#pragma unroll
      for (int r = 0; r < 4; ++r) {
        int g0 = row0 + kg * 4 + r;
        if (g0 < M) C[(size_t)g0 * ldc + gc] = accA[nt][r];
        int g1 = row0 + 16 + kg * 4 + r;
        if (g1 < M) C[(size_t)g1 * ldc + gc] = accB[nt][r];
      }
    }
  }
}

// ---------------- SAGE aggregation (wave per node) -> h0 bf16 hi/lo --------
// yI: packed 2xbf16 per (node, d) uint. 8-wide unrolled gathers (MLP).
__global__ __launch_bounds__(256) void sage_agg(const float* __restrict__ z,
                                                const unsigned* __restrict__ yI,
                                                const int* __restrict__ row_start,
                                                const int* __restrict__ csr_src,
                                                const float* __restrict__ b,
                                                unsigned short* __restrict__ h0h,
                                                unsigned short* __restrict__ h0l, int N) {
  int wid = threadIdx.x >> 6;
  int lane = threadIdx.x & 63;
  int n = blockIdx.x * 4 + wid;
  if (n >= N) return;
  int s = row_start[n], e = row_start[n + 1];
  float a0 = 0.f, a1 = 0.f;
  int i = s;
  for (; i + 7 < e; i += 8) {
    unsigned v0 = yI[(size_t)csr_src[i] * 64 + lane];
    unsigned v1 = yI[(size_t)csr_src[i + 1] * 64 + lane];
    unsigned v2 = yI[(size_t)csr_src[i + 2] * 64 + lane];
    unsigned v3 = yI[(size_t)csr_src[i + 3] * 64 + lane];
    unsigned v4 = yI[(size_t)csr_src[i + 4] * 64 + lane];
    unsigned v5 = yI[(size_t)csr_src[i + 5] * 64 + lane];
    unsigned v6 = yI[(size_t)csr_src[i + 6] * 64 + lane];
    unsigned v7 = yI[(size_t)csr_src[i + 7] * 64 + lane];
    float2 f0 = unpk(v0), f1 = unpk(v1), f2 = unpk(v2), f3 = unpk(v3);
    float2 f4 = unpk(v4), f5 = unpk(v5), f6 = unpk(v6), f7 = unpk(v7);
    a0 += f0.x + f1.x + f2.x + f3.x + f4.x + f5.x + f6.x + f7.x;
    a1 += f0.y + f1.y + f2.y + f3.y + f4.y + f5.y + f6.y + f7.y;
  }
  for (; i < e; ++i) {
    float2 f = unpk(yI[(size_t)csr_src[i] * 64 + lane]);
    a0 += f.x;
    a1 += f.y;
  }
  float inv = 1.0f / fmaxf((float)(e - s), 1.0f);
  size_t base = (size_t)n * 128;
  float v0 = elu_f(z[base + lane] + a0 * inv + b[lane]);
  float v1 = elu_f(z[base + 64 + lane] + a1 * inv + b[64 + lane]);
  unsigned short hh0 = f2bf(v0), hh1 = f2bf(v1);
  h0h[base + lane] = hh0;
  h0l[base + lane] = f2bf(v0 - bf2f(hh0));
  h0h[base + 64 + lane] = hh1;
  h0l[base + 64 + lane] = f2bf(v1 - bf2f(hh1));
}

// ---------------- per-node attention logits (layer 1) ----------------------
__global__ __launch_bounds__(256) void elr1_kernel(const unsigned* __restrict__ featI,
                                                   const float* __restrict__ al,
                                                   const float* __restrict__ ar,
                                                   float2* __restrict__ el,
                                                   float2* __restrict__ er, int N) {
  int wid = threadIdx.x >> 6;
  int lane = threadIdx.x & 63;
  int n = blockIdx.x * 4 + wid;
  if (n >= N) return;
  float2 f = unpk(featI[(size_t)n * 64 + lane]);
  float e0 = wave_sum(f.x * al[lane]);
  float e1 = wave_sum(f.y * al[64 + lane]);
  float r0 = wave_sum(f.x * ar[lane]);
  float r1 = wave_sum(f.y * ar[64 + lane]);
  if (lane == 0) {
    el[n] = make_float2(e0, e1);
    er[n] = make_float2(r0, r1);
  }
}

// ---------------- attn1: thread per node, softmax weights ------------------
__global__ __launch_bounds__(256) void attn1_kernel(const float2* __restrict__ el,
                                                    const float2* __restrict__ er,
                                                    const int* __restrict__ row_start,
                                                    const int* __restrict__ csr_src,
                                                    float2* __restrict__ alpha,
                                                    float2* __restrict__ inv_s, int N) {
  int n = blockIdx.x * 256 + threadIdx.x;
  if (n >= N) return;
  int beg = row_start[n], end = row_start[n + 1];
  float2 r = er[n];
  float m0 = -INFINITY, m1 = -INFINITY;
  for (int i = beg; i < end; ++i) {
    float2 l = el[csr_src[i]];
    float e0 = l.x + r.x;
    e0 = e0 > 0.f ? e0 : 0.2f * e0;
    float e1 = l.y + r.y;
    e1 = e1 > 0.f ? e1 : 0.2f * e1;
    alpha[i] = make_float2(e0, e1);
    m0 = fmaxf(m0, e0);
    m1 = fmaxf(m1, e1);
  }
  float s0 = 0.f, s1 = 0.f;
  for (int i = beg; i < end; ++i) {
    float2 a = alpha[i];
    float p0 = __expf(a.x - m0);
    float p1 = __expf(a.y - m1);
    s0 += p0;
    s1 += p1;
    alpha[i] = make_float2(p0, p1);
  }
  inv_s[n] = make_float2(1.0f / fmaxf(s0, 1e-9f), 1.0f / fmaxf(s1, 1e-9f));
}

// ---------------- fused GAT layer 1 aggregation -> h1 bf16 hi/lo -----------
// 8-wide unrolled gathers (MLP).
__global__ __launch_bounds__(256) void gat1_agg(const unsigned* __restrict__ featI,
                                                const float2* __restrict__ alpha,
                                                const float2* __restrict__ inv_s,
                                                const int* __restrict__ row_start,
                                                const int* __restrict__ csr_src,
                                                const float* __restrict__ b,
                                                unsigned short* __restrict__ h1h,
                                                unsigned short* __restrict__ h1l, int N) {
  int wid = threadIdx.x >> 6;
  int lane = threadIdx.x & 63;
  int n = blockIdx.x * 4 + wid;
  if (n >= N) return;
  int beg = row_start[n], end = row_start[n + 1];
  float a0 = 0.f, a1 = 0.f;
  int i = beg;
  for (; i + 7 < end; i += 8) {
    unsigned v0 = featI[(size_t)csr_src[i] * 64 + lane];
    unsigned v1 = featI[(size_t)csr_src[i + 1] * 64 + lane];
    unsigned v2 = featI[(size_t)csr_src[i + 2] * 64 + lane];
    unsigned v3 = featI[(size_t)csr_src[i + 3] * 64 + lane];
    unsigned v4 = featI[(size_t)csr_src[i + 4] * 64 + lane];
    unsigned v5 = featI[(size_t)csr_src[i + 5] * 64 + lane];
    unsigned v6 = featI[(size_t)csr_src[i + 6] * 64 + lane];
    unsigned v7 = featI[(size_t)csr_src[i + 7] * 64 + lane];
    float2 p0 = alpha[i], p1 = alpha[i + 1], p2 = alpha[i + 2], p3 = alpha[i + 3];
    float2 p4 = alpha[i + 4], p5 = alpha[i + 5], p6 = alpha[i + 6], p7 = alpha[i + 7];
    float2 f0 = unpk(v0), f1 = unpk(v1), f2 = unpk(v2), f3 = unpk(v3);
    float2 f4 = unpk(v4), f5 = unpk(v5), f6 = unpk(v6), f7 = unpk(v7);
    a0 = fmaf(p0.x, f0.x, a0); a1 = fmaf(p0.y, f0.y, a1);
    a0 = fmaf(p1.x, f1.x, a0); a1 = fmaf(p1.y, f1.y, a1);
    a0 = fmaf(p2.x, f2.x, a0); a1 = fmaf(p2.y, f2.y, a1);
    a0 = fmaf(p3.x, f3.x, a0); a1 = fmaf(p3.y, f3.y, a1);
    a0 = fmaf(p4.x, f4.x, a0); a1 = fmaf(p4.y, f4.y, a1);
    a0 = fmaf(p5.x, f5.x, a0); a1 = fmaf(p5.y, f5.y, a1);
    a0 = fmaf(p6.x, f6.x, a0); a1 = fmaf(p6.y, f6.y, a1);
    a0 = fmaf(p7.x, f7.x, a0); a1 = fmaf(p7.y, f7.y, a1);
  }
  for (; i < end; ++i) {
    float2 p = alpha[i];
    float2 f = unpk(featI[(size_t)csr_src[i] * 64 + lane]);
    a0 = fmaf(p.x, f.x, a0);
    a1 = fmaf(p.y, f.y, a1);
  }
  float2 is = inv_s[n];
  float o0 = elu_f(a0 * is.x + b[lane]);
  float o1 = elu_f(a1 * is.y + b[64 + lane]);
  size_t base = (size_t)n * 128;
  unsigned short hh0 = f2bf(o0), hh1 = f2bf(o1);
  h1h[base + lane] = hh0;
  h1l[base + lane] = f2bf(o0 - bf2f(hh0));
  h1h[base + 64 + lane] = hh1;
  h1l[base + 64 + lane] = f2bf(o1 - bf2f(hh1));
}

// ---------------- per-node attention logits (layer 2) ----------------------
__global__ __launch_bounds__(256) void elr2_kernel(const unsigned short* __restrict__ feat,  // bf16 ld48
                                                   const float* __restrict__ al,
                                                   const float* __restrict__ ar,
                                                   float* __restrict__ el,
                                                   float* __restrict__ er, int N) {
  int wid = threadIdx.x >> 6;
  int lane = threadIdx.x & 63;
  int n = blockIdx.x * 4 + wid;
  if (n >= N) return;
  float f = 0.f, a = 0.f, r = 0.f;
  if (lane < 47) {
    f = bf2f(feat[(size_t)n * 48 + lane]);
    a = al[lane];
    r = ar[lane];
  }
  float e = wave_sum(f * a);
  float rr = wave_sum(f * r);
  if (lane == 0) {
    el[n] = e;
    er[n] = rr;
  }
}

// ---------------- attn2: thread per node ----------------------------------
__global__ __launch_bounds__(256) void attn2_kernel(const float* __restrict__ el,
                                                    const float* __restrict__ er,
                                                    const int* __restrict__ row_start,
                                                    const int* __restrict__ csr_src,
                                                    float* __restrict__ alpha,
                                                    float* __restrict__ inv_s, int N) {
  int n = blockIdx.x * 256 + threadIdx.x;
  if (n >= N) return;
  int beg = row_start[n], end = row_start[n + 1];
  float r = er[n];
  float m = -INFINITY;
  for (int i = beg; i < end; ++i) {
    float e = el[csr_src[i]] + r;
    e = e > 0.f ? e : 0.2f * e;
    alpha[i] = e;
    m = fmaxf(m, e);
  }
  float s = 0.f;
  for (int i = beg; i < end; ++i) {
    float p = __expf(alpha[i] - m);
    s += p;
    alpha[i] = p;
  }
  inv_s[n] = 1.0f / fmaxf(s, 1e-9f);
}

// ---------------- fused GAT layer 2 aggregation -> d_out ------------------
// 8-wide unrolled gathers (MLP).
__global__ __launch_bounds__(256) void gat2_agg(const unsigned short* __restrict__ feat,  // bf16 ld48
                                                const float* __restrict__ alpha,
                                                const float* __restrict__ inv_s,
                                                const int* __restrict__ row_start,
                                                const int* __restrict__ csr_src,
                                                const float* __restrict__ b,
                                                float* __restrict__ out, int N) {
  int wid = threadIdx.x >> 6;
  int lane = threadIdx.x & 63;
  int n = blockIdx.x * 4 + wid;
  if (n >= N) return;
  int beg = row_start[n], end = row_start[n + 1];
  int lidx = lane < 47 ? lane : 0;
  float acc = 0.f;
  int i = beg;
  for (; i + 7 < end; i += 8) {
    float g0 = bf2f(feat[(size_t)csr_src[i] * 48 + lidx]);
    float g1 = bf2f(feat[(size_t)csr_src[i + 1] * 48 + lidx]);
    float g2 = bf2f(feat[(size_t)csr_src[i + 2] * 48 + lidx]);
    float g3 = bf2f(feat[(size_t)csr_src[i + 3] * 48 + lidx]);
    float g4 = bf2f(feat[(size_t)csr_src[i + 4] * 48 + lidx]);
    float g5 = bf2f(feat[(size_t)csr_src[i + 5] * 48 + lidx]);
    float g6 = bf2f(feat[(size_t)csr_src[i + 6] * 48 + lidx]);
    float g7 = bf2f(feat[(size_t)csr_src[i + 7] * 48 + lidx]);
    float p0 = alpha[i], p1 = alpha[i + 1], p2 = alpha[i + 2], p3 = alpha[i + 3];
    float p4 = alpha[i + 4], p5 = alpha[i + 5], p6 = alpha[i + 6], p7 = alpha[i + 7];
    acc = fmaf(p0, g0, acc);
    acc = fmaf(p1, g1, acc);
    acc = fmaf(p2, g2, acc);
    acc = fmaf(p3, g3, acc);
    acc = fmaf(p4, g4, acc);
    acc = fmaf(p5, g5, acc);
    acc = fmaf(p6, g6, acc);
    acc = fmaf(p7, g7, acc);
  }
  for (; i < end; ++i) {
    acc = fmaf(alpha[i], bf2f(feat[(size_t)csr_src[i] * 48 + lidx]), acc);
  }
  if (lane < 47) {
    out[(size_t)n * 47 + lane] = acc * inv_s[n] + b[lane];
  }
}

// ---------------------------------------------------------------------------
extern "C" void kernel_launch(void* const* d_in, const int* in_sizes, int n_in,
                              void* d_out, int out_size, void* d_ws, size_t ws_size,
                              hipStream_t stream) {
  const float* x = (const float*)d_in[0];
  const int* src = (const int*)d_in[1];
  const int* dst = (const int*)d_in[2];
  const float* sage_w_self = (const float*)d_in[3];
  const float* sage_w_neigh = (const float*)d_in[4];
  const float* sage_b = (const float*)d_in[5];
  const float* gat1_w = (const float*)d_in[6];
  const float* gat1_al = (const float*)d_in[7];
  const float* gat1_ar = (const float*)d_in[8];
  const float* gat1_b = (const float*)d_in[9];
  const float* gat2_w = (const float*)d_in[10];
  const float* gat2_al = (const float*)d_in[11];
  const float* gat2_ar = (const float*)d_in[12];
  const float* gat2_b = (const float*)d_in[13];
  float* out = (float*)d_out;

  const int N = in_sizes[0] / 256;
  const int E = in_sizes[1];

  char* ws = (char*)d_ws;
  size_t off = 0;
  auto alloc = [&](size_t bytes) {
    size_t o = off;
    off += (bytes + 255) & ~(size_t)255;
    return o;
  };
  int* deg_i = (int*)(ws + alloc((size_t)N * 4));
  int* row_start = (int*)(ws + alloc((size_t)(N + 1) * 4));
  int* cursor = (int*)(ws + alloc((size_t)N * 4));
  int* csr_src = (int*)(ws + alloc((size_t)E * 4));
  int* psum = (int*)(ws + alloc(((size_t)N / 1024 + 2) * 4));
  float* bufA = (float*)(ws + alloc((size_t)N * 128 * 4));       // z; later alpha1/alpha2
  unsigned* bufG = (unsigned*)(ws + alloc((size_t)N * 64 * 4));  // yI -> feat1I -> feat2b
  unsigned short* bufX = (unsigned short*)(ws + alloc((size_t)N * 256 * 2 * 2));  // xh|xl
  unsigned short* wt_sh = (unsigned short*)(ws + alloc(128 * 256 * 2));
  unsigned short* wt_sl = (unsigned short*)(ws + alloc(128 * 256 * 2));
  unsigned short* wt_nh = (unsigned short*)(ws + alloc(128 * 256 * 2));
  unsigned short* wt_nl = (unsigned short*)(ws + alloc(128 * 256 * 2));
  unsigned short* wt_1h = (unsigned short*)(ws + alloc(128 * 128 * 2));
  unsigned short* wt_1l = (unsigned short*)(ws + alloc(128 * 128 * 2));
  unsigned short* wt_2h = (unsigned short*)(ws + alloc(48 * 128 * 2));
  unsigned short* wt_2l = (unsigned short*)(ws + alloc(48 * 128 * 2));
  float2* el1 = (float2*)(ws + alloc((size_t)N * 8));
  float2* er1 = (float2*)(ws + alloc((size_t)N * 8));
  float* el2 = (float*)(ws + alloc((size_t)N * 4));
  float* er2 = (float*)(ws + alloc((size_t)N * 4));
  float2* inv_s1 = (float2*)(ws + alloc((size_t)N * 8));
  float* inv_s2 = (float*)(ws + alloc((size_t)N * 4));
  (void)ws_size;
  (void)n_in;
  (void)out_size;

  // lifetimes:
  unsigned short* xh = (unsigned short*)bufX;       // dead after L0 gemm
  unsigned short* xl = bufX + (size_t)N * 256;      // dead after L0 gemm
  float* z = bufA;                                  // dead after sage_agg
  unsigned* yI = bufG;                              // dead after sage_agg
  unsigned short* h0h = bufX;                       // reuse xh region
  unsigned short* h0l = bufX + (size_t)N * 128;
  unsigned* feat1I = bufG;                          // reuse yI; dead after gat1_agg
  float2* alpha1 = (float2*)bufA;                   // reuse z; dead after gat1_agg
  unsigned short* h1h = bufX + (size_t)N * 256;     // reuse xl region
  unsigned short* h1l = bufX + (size_t)N * 256 + (size_t)N * 128;
  unsigned short* feat2b = (unsigned short*)bufG;   // reuse feat1I
  float* alpha2 = bufA;                             // reuse alpha1

  hipMemsetAsync(deg_i, 0, (size_t)N * 4, stream);
  hipMemsetAsync(cursor, 0, (size_t)N * 4, stream);

  const int eb = (E + 255) / 256;
  const int nb4 = (N + 3) / 4;
  const int nb256 = (N + 255) / 256;
  const int gx = (N + 127) / 128;
  const int PB = (N + 1023) / 1024;

  split_x<<<2048, 256, 0, stream>>>(x, xh, xl, N * 64);
  prep_w<<<(128 * 256 + 255) / 256, 256, 0, stream>>>(sage_w_self, 128, 256, 128, wt_sh, wt_sl);
  prep_w<<<(128 * 256 + 255) / 256, 256, 0, stream>>>(sage_w_neigh, 128, 256, 128, wt_nh, wt_nl);
  prep_w<<<(128 * 128 + 255) / 256, 256, 0, stream>>>(gat1_w, 128, 128, 128, wt_1h, wt_1l);
  prep_w<<<(48 * 128 + 255) / 256, 256, 0, stream>>>(gat2_w, 47, 128, 48, wt_2h, wt_2l);

  deg_kernel<<<eb, 256, 0, stream>>>(dst, deg_i, E);
  scan_partial<<<PB, 256, 0, stream>>>(deg_i, psum, N);
  scan_psum<<<1, 64, 0, stream>>>(psum, PB);
  scan_final<<<PB, 256, 0, stream>>>(deg_i, psum, row_start, N, E);
  scatter_kernel<<<eb, 256, 0, stream>>>(src, dst, row_start, cursor, csr_src, E);

  // layer 0: y=0 -> z = x@W_self (f32, ldc=128 floats),
  //          y=1 -> yI = x@W_neigh (packed bf16 ilv, ldu=64 uints)
  {
    dim3 grid(gx, 2);
    gemm_mfma<256, 8><<<grid, 256, 0, stream>>>(xh, xl, wt_sh, wt_sl, wt_nh, wt_nl,
                                                z, yI, 128, N, 128, 0, 1);
  }
  sage_agg<<<nb4, 256, 0, stream>>>(z, yI, row_start, csr_src, sage_b, h0h, h0l, N);

  // GAT layer 1: feat1I = h0 @ gat1_w (packed bf16 ilv, ldc=128 -> ldu=64 uints)
  {
    dim3 grid(gx, 1);
    gemm_mfma<128, 8><<<grid, 256, 0, stream>>>(h0h, h0l, wt_1h, wt_1l, wt_1h, wt_1l,
                                                feat1I, feat1I, 128, N, 128, 1, 1);
  }
  elr1_kernel<<<nb4, 256, 0, stream>>>(feat1I, gat1_al, gat1_ar, el1, er1, N);
  attn1_kernel<<<nb256, 256, 0, stream>>>(el1, er1, row_start, csr_src, alpha1, inv_s1, N);
  gat1_agg<<<nb4, 256, 0, stream>>>(feat1I, alpha1, inv_s1, row_start, csr_src, gat1_b,
                                    h1h, h1l, N);

  // GAT layer 2: feat2b = h1 @ gat2_w (bf16 std, ldc=48 ushorts)
  {
    dim3 grid(gx, 1);
    gemm_mfma<128, 3><<<grid, 256, 0, stream>>>(h1h, h1l, wt_2h, wt_2l, wt_2h, wt_2l,
                                                feat2b, feat2b, 48, N, 47, 2, 2);
  }
  elr2_kernel<<<nb4, 256, 0, stream>>>(feat2b, gat2_al, gat2_ar, el2, er2, N);
  attn2_kernel<<<nb256, 256, 0, stream>>>(el2, er2, row_start, csr_src, alpha2, inv_s2, N);
  gat2_agg<<<nb4, 256, 0, stream>>>(feat2b, alpha2, inv_s2, row_start, csr_src, gat2_b, out, N);
}